// Round 2
// baseline (2740.610 us; speedup 1.0000x reference)
//
#include <hip/hip_runtime.h>
#include <hip/hip_bf16.h>

typedef __bf16 bf16;
typedef __bf16 bf16x4 __attribute__((ext_vector_type(4)));
typedef __bf16 bf16x8 __attribute__((ext_vector_type(8)));
typedef float f32x4 __attribute__((ext_vector_type(4)));

#define PHI_SCALE  0.31947154f   // 96^-0.25
#define DIAG_SCALE 0.05103104f   // 0.5 * 96^-0.5
#define FEAT_SCALE 0.0625f       // 256^-0.5

// ---------------- reductions ----------------
__device__ __forceinline__ float waveSum(float v) {
#pragma unroll
  for (int o = 32; o > 0; o >>= 1) v += __shfl_xor(v, o, 64);
  return v;
}
__device__ __forceinline__ float waveMax(float v) {
#pragma unroll
  for (int o = 32; o > 0; o >>= 1) v = fmaxf(v, __shfl_xor(v, o, 64));
  return v;
}
__device__ __forceinline__ float blockSum(float v) {
  __shared__ float tmp[4];
  v = waveSum(v);
  if ((threadIdx.x & 63) == 0) tmp[threadIdx.x >> 6] = v;
  __syncthreads();
  float r = tmp[0] + tmp[1] + tmp[2] + tmp[3];
  __syncthreads();
  return r;
}
__device__ __forceinline__ float blockMax(float v) {
  __shared__ float tmp[4];
  v = waveMax(v);
  if ((threadIdx.x & 63) == 0) tmp[threadIdx.x >> 6] = v;
  __syncthreads();
  float r = fmaxf(fmaxf(tmp[0], tmp[1]), fmaxf(tmp[2], tmp[3]));
  __syncthreads();
  return r;
}

// ---------------- patch embed (f32 in, f32 out) ----------------
__global__ __launch_bounds__(256) void patch_kernel(const float* __restrict__ mel,
    const float* __restrict__ pw, const float* __restrict__ pb,
    const float* __restrict__ pos, float* __restrict__ x) {
  __shared__ float patch[256];
  int blk = blockIdx.x;            // b*512 + n
  int b = blk >> 9, n = blk & 511;
  int r0 = (n >> 3) << 4, c0 = (n & 7) << 4;
  int t = threadIdx.x;
  {
    int i = t >> 4, j = t & 15;
    patch[t] = mel[((size_t)b * 1024 + r0 + i) * 128 + c0 + j];
  }
  __syncthreads();
  for (int c = 0; c < 3; c++) {
    int d = t + c * 256;
    const f32x4* wr = (const f32x4*)(pw + (size_t)d * 256);
    float acc = 0.f;
#pragma unroll 8
    for (int p4 = 0; p4 < 64; p4++) {
      f32x4 wv = wr[p4];
      acc += patch[p4 * 4 + 0] * wv[0] + patch[p4 * 4 + 1] * wv[1]
           + patch[p4 * 4 + 2] * wv[2] + patch[p4 * 4 + 3] * wv[3];
    }
    x[((size_t)b * 512 + n) * 768 + d] = acc + pb[d] + pos[(size_t)n * 768 + d];
  }
}

// ---------------- f32 -> bf16 convert ----------------
__global__ __launch_bounds__(256) void cvt_kernel(const float* __restrict__ src,
    bf16* __restrict__ dst, int n) {
  int i = blockIdx.x * 256 + threadIdx.x;
  if (i < n) dst[i] = (bf16)src[i];
}

// ---------------- transpose + convert: src f32 (K x N) -> dst bf16 (N x K), batched z ----------------
__global__ __launch_bounds__(256) void transpose_cvt_kernel(const float* __restrict__ src,
    bf16* __restrict__ dst, int K, int N) {
  __shared__ float lds[64][65];
  size_t zoff = (size_t)blockIdx.z * K * N;
  int n0 = blockIdx.x * 64, k0 = blockIdx.y * 64;
  int t = threadIdx.x;
  for (int idx = t; idx < 4096; idx += 256) {
    int r = idx >> 6, c = idx & 63;
    lds[r][c] = src[zoff + (size_t)(k0 + r) * N + n0 + c];
  }
  __syncthreads();
  for (int idx = t; idx < 4096; idx += 256) {
    int r = idx >> 6, c = idx & 63;
    dst[zoff + (size_t)(n0 + r) * K + k0 + c] = (bf16)lds[c][r];
  }
}

// ---------------- transpose bf16 (K x N) -> bf16 (N x K), batched z ----------------
__global__ __launch_bounds__(256) void transpose_bf_kernel(const bf16* __restrict__ src,
    bf16* __restrict__ dst, int K, int N) {
  __shared__ bf16 lds[64][65];
  size_t zoff = (size_t)blockIdx.z * K * N;
  int n0 = blockIdx.x * 64, k0 = blockIdx.y * 64;
  int t = threadIdx.x;
  for (int idx = t; idx < 4096; idx += 256) {
    int r = idx >> 6, c = idx & 63;
    lds[r][c] = src[zoff + (size_t)(k0 + r) * N + n0 + c];
  }
  __syncthreads();
  for (int idx = t; idx < 4096; idx += 256) {
    int r = idx >> 6, c = idx & 63;
    dst[zoff + (size_t)(n0 + r) * K + k0 + c] = lds[c][r];
  }
}

// ---------------- layernorm: x(f32, rows x 768) -> h(bf16) ----------------
__global__ __launch_bounds__(256) void ln_kernel(const float* __restrict__ x,
    const float* __restrict__ s, const float* __restrict__ bta, bf16* __restrict__ h) {
  int row = blockIdx.x;
  const float* xr = x + (size_t)row * 768;
  int t = threadIdx.x;
  float v0 = xr[t], v1 = xr[t + 256], v2 = xr[t + 512];
  float mu = blockSum(v0 + v1 + v2) * (1.f / 768.f);
  float d0 = v0 - mu, d1 = v1 - mu, d2 = v2 - mu;
  float var = blockSum(d0 * d0 + d1 * d1 + d2 * d2) * (1.f / 768.f);
  float inv = rsqrtf(var + 1e-5f);
  bf16* hr = h + (size_t)row * 768;
  hr[t]       = (bf16)(d0 * inv * s[t]       + bta[t]);
  hr[t + 256] = (bf16)(d1 * inv * s[t + 256] + bta[t + 256]);
  hr[t + 512] = (bf16)(d2 * inv * s[t + 512] + bta[t + 512]);
}

// ---------------- main 128x128 MFMA GEMM ----------------
// C(MxN) = A(MxK,row-major,bf16) @ B(NxK,row-major,bf16)^T ; bias f32
// mode 0: outb = bf16(acc+bias); mode 1: outb = bf16(gelu(acc+bias));
// mode 2: xout = xin + acc + bias (f32)
__global__ __launch_bounds__(256) void gemm128(const bf16* __restrict__ A,
    const bf16* __restrict__ B, const float* __restrict__ bias, bf16* __restrict__ outb,
    const float* __restrict__ xin, float* __restrict__ xout, int M, int N, int K, int mode) {
  __shared__ __attribute__((aligned(16))) bf16 lds_a[128 * 40];
  __shared__ __attribute__((aligned(16))) bf16 lds_b[128 * 40];
  const int t = threadIdx.x;
  const int m0 = blockIdx.x * 128, n0 = blockIdx.y * 128;
  const int wave = t >> 6, lane = t & 63;
  const int quad = lane >> 4, id = lane & 15;
  const int wr = (wave >> 1) * 64, wc = (wave & 1) * 64;
  const int row = t >> 2, kof = (t & 3) * 8;
  f32x4 acc[4][4] = {};
  for (int k0 = 0; k0 < K; k0 += 32) {
    *(bf16x8*)&lds_a[row * 40 + kof]        = *(const bf16x8*)&A[(size_t)(m0 + row) * K + k0 + kof];
    *(bf16x8*)&lds_a[(row + 64) * 40 + kof] = *(const bf16x8*)&A[(size_t)(m0 + row + 64) * K + k0 + kof];
    *(bf16x8*)&lds_b[row * 40 + kof]        = *(const bf16x8*)&B[(size_t)(n0 + row) * K + k0 + kof];
    *(bf16x8*)&lds_b[(row + 64) * 40 + kof] = *(const bf16x8*)&B[(size_t)(n0 + row + 64) * K + k0 + kof];
    __syncthreads();
    bf16x8 af[4], bg[4];
#pragma unroll
    for (int i = 0; i < 4; i++) af[i] = *(bf16x8*)&lds_a[(wr + i * 16 + id) * 40 + quad * 8];
#pragma unroll
    for (int j = 0; j < 4; j++) bg[j] = *(bf16x8*)&lds_b[(wc + j * 16 + id) * 40 + quad * 8];
#pragma unroll
    for (int i = 0; i < 4; i++)
#pragma unroll
      for (int j = 0; j < 4; j++)
        acc[i][j] = __builtin_amdgcn_mfma_f32_16x16x32_bf16(af[i], bg[j], acc[i][j], 0, 0, 0);
    __syncthreads();
  }
#pragma unroll
  for (int i = 0; i < 4; i++) {
#pragma unroll
    for (int j = 0; j < 4; j++) {
#pragma unroll
      for (int r = 0; r < 4; r++) {
        int rr = m0 + wr + i * 16 + quad * 4 + r;
        int cc = n0 + wc + j * 16 + id;
        float v = acc[i][j][r] + bias[cc];
        if (mode == 0) {
          outb[(size_t)rr * N + cc] = (bf16)v;
        } else if (mode == 1) {
          outb[(size_t)rr * N + cc] = (bf16)(0.5f * v * (1.0f + erff(v * 0.70710678f)));
        } else {
          xout[(size_t)rr * N + cc] = xin[(size_t)rr * N + cc] + v;
        }
      }
    }
  }
}

// ---------------- phi u GEMM: u[bh, n, m] = PHI_SCALE * (q_row . proj_row_m) ----------------
__global__ __launch_bounds__(256) void phi_u_gemm(const bf16* __restrict__ qkv,
    const bf16* __restrict__ proj, float* __restrict__ u, int which) {
  __shared__ __attribute__((aligned(16))) bf16 lds_a[128 * 40];
  __shared__ __attribute__((aligned(16))) bf16 lds_b[128 * 40];
  const int t = threadIdx.x;
  const int bh = blockIdx.z, b = bh >> 3, h = bh & 7;
  const int n0 = blockIdx.x * 128, f0 = blockIdx.y * 128;
  const bf16* A = qkv + (size_t)b * 512 * 2304 + which * 768 + h * 96;  // row stride 2304
  const int wave = t >> 6, lane = t & 63;
  const int quad = lane >> 4, id = lane & 15;
  const int wr = (wave >> 1) * 64, wc = (wave & 1) * 64;
  const int row = t >> 2, kof = (t & 3) * 8;
  f32x4 acc[4][4] = {};
  for (int k0 = 0; k0 < 96; k0 += 32) {
    *(bf16x8*)&lds_a[row * 40 + kof]        = *(const bf16x8*)&A[(size_t)(n0 + row) * 2304 + k0 + kof];
    *(bf16x8*)&lds_a[(row + 64) * 40 + kof] = *(const bf16x8*)&A[(size_t)(n0 + row + 64) * 2304 + k0 + kof];
    *(bf16x8*)&lds_b[row * 40 + kof]        = *(const bf16x8*)&proj[(size_t)(f0 + row) * 96 + k0 + kof];
    *(bf16x8*)&lds_b[(row + 64) * 40 + kof] = *(const bf16x8*)&proj[(size_t)(f0 + row + 64) * 96 + k0 + kof];
    __syncthreads();
    bf16x8 af[4], bg[4];
#pragma unroll
    for (int i = 0; i < 4; i++) af[i] = *(bf16x8*)&lds_a[(wr + i * 16 + id) * 40 + quad * 8];
#pragma unroll
    for (int j = 0; j < 4; j++) bg[j] = *(bf16x8*)&lds_b[(wc + j * 16 + id) * 40 + quad * 8];
#pragma unroll
    for (int i = 0; i < 4; i++)
#pragma unroll
      for (int j = 0; j < 4; j++)
        acc[i][j] = __builtin_amdgcn_mfma_f32_16x16x32_bf16(af[i], bg[j], acc[i][j], 0, 0, 0);
    __syncthreads();
  }
#pragma unroll
  for (int i = 0; i < 4; i++)
#pragma unroll
    for (int j = 0; j < 4; j++)
#pragma unroll
      for (int r = 0; r < 4; r++) {
        int rr = n0 + wr + i * 16 + quad * 4 + r;
        int cc = f0 + wc + j * 16 + id;
        u[((size_t)bh * 512 + rr) * 256 + cc] = acc[i][j][r] * PHI_SCALE;
      }
}

// ---------------- diag: 0.5*d^-0.5*||row||^2 for q(0..32767) and k(32768..65535) ----------------
__global__ __launch_bounds__(256) void diag_kernel(const bf16* __restrict__ qkv,
    float* __restrict__ diag) {
  int rowid = blockIdx.x * 4 + (threadIdx.x >> 6);
  int lane = threadIdx.x & 63;
  int which = rowid >> 15, rem = rowid & 32767;
  int bh = rem >> 9, n = rem & 511;
  int b = bh >> 3, h = bh & 7;
  const bf16* q = qkv + ((size_t)b * 512 + n) * 2304 + which * 768 + h * 96;
  float v = 0.f;
  for (int e = lane; e < 96; e += 64) { float xv = (float)q[e]; v += xv * xv; }
  v = waveSum(v);
  if (lane == 0) diag[rowid] = DIAG_SCALE * v;
}

// ---------------- pq: per-row max stab ----------------
__global__ __launch_bounds__(256) void pq_kernel(const float* __restrict__ u,
    const float* __restrict__ diag, bf16* __restrict__ pq) {
  int r = blockIdx.x;  // bh*512+n
  int t = threadIdx.x;
  float v = u[(size_t)r * 256 + t];
  float mx = blockMax(v);
  float arg = fminf(v - diag[r] - mx, 0.f);
  pq[(size_t)r * 256 + t] = (bf16)((expf(arg) + 1e-4f) * FEAT_SCALE);
}

// ---------------- kmax: global max over u_k ----------------
__global__ __launch_bounds__(256) void kmax1_kernel(const float* __restrict__ u, float* __restrict__ bmax) {
  int t = threadIdx.x;
  size_t gid = (size_t)blockIdx.x * 256 + t;
  float m = -1e30f;
  for (size_t i = gid; i < (size_t)64 * 512 * 256; i += (size_t)2048 * 256) m = fmaxf(m, u[i]);
  m = blockMax(m);
  if (t == 0) bmax[blockIdx.x] = m;
}
__global__ __launch_bounds__(256) void kmax2_kernel(const float* __restrict__ bmax, float* __restrict__ kmaxbuf) {
  int t = threadIdx.x;
  float m = -1e30f;
  for (int i = t; i < 2048; i += 256) m = fmaxf(m, bmax[i]);
  m = blockMax(m);
  if (t == 0) kmaxbuf[0] = m;
}

// ---------------- pk: global stab ----------------
__global__ __launch_bounds__(256) void pk_kernel(const float* __restrict__ u,
    const float* __restrict__ diagk, const float* __restrict__ kmaxbuf, bf16* __restrict__ pk) {
  int r = blockIdx.x;
  int t = threadIdx.x;
  float stab = kmaxbuf[0];
  float v = u[(size_t)r * 256 + t];
  float arg = fminf(v - diagk[r] - stab, 0.f);
  pk[(size_t)r * 256 + t] = (bf16)((expf(arg) + 1e-4f) * FEAT_SCALE);
}

// ---------------- ksum[bh,m] = sum_n pk[bh,n,m] ----------------
__global__ __launch_bounds__(256) void ksum_kernel(const bf16* __restrict__ pk, float* __restrict__ ksum) {
  int bh = blockIdx.x, m = threadIdx.x;
  const bf16* p = pk + (size_t)bh * 512 * 256;
  float s = 0.f;
  for (int n = 0; n < 512; n++) s += (float)p[(size_t)n * 256 + m];
  ksum[bh * 256 + m] = s;
}

// ---------------- vT[bh,e,n] = qkv[b,n,1536+h*96+e] ----------------
__global__ __launch_bounds__(256) void vt_kernel(const bf16* __restrict__ qkv, bf16* __restrict__ vT) {
  __shared__ bf16 lds[64][97];
  int bh = blockIdx.y, b = bh >> 3, h = bh & 7;
  int n0 = blockIdx.x * 64;
  int t = threadIdx.x;
  const bf16* src = qkv + ((size_t)b * 512 + n0) * 2304 + 1536 + h * 96;
  for (int idx = t; idx < 6144; idx += 256) {
    int r = idx / 96, c = idx % 96;
    lds[r][c] = src[(size_t)r * 2304 + c];
  }
  __syncthreads();
  bf16* dst = vT + (size_t)bh * 96 * 512 + n0;
  for (int idx = t; idx < 6144; idx += 256) {
    int e = idx >> 6, nn = idx & 63;
    dst[(size_t)e * 512 + nn] = lds[nn][e];
  }
}

// ---------------- ctx GEMM: ctxT[bh,e,m] = sum_n pkT[bh,m,n]*vT[bh,e,n] ----------------
__global__ __launch_bounds__(256) void ctx_gemm(const bf16* __restrict__ pkT,
    const bf16* __restrict__ vT, bf16* __restrict__ ctxT) {
  __shared__ __attribute__((aligned(16))) bf16 lds_a[64 * 40];
  __shared__ __attribute__((aligned(16))) bf16 lds_b[96 * 40];
  const int t = threadIdx.x;
  const int bh = blockIdx.y, m0 = blockIdx.x * 64;
  const bf16* A = pkT + (size_t)bh * 256 * 512;
  const bf16* B = vT + (size_t)bh * 96 * 512;
  const int wave = t >> 6, lane = t & 63;
  const int quad = lane >> 4, id = lane & 15;
  const int row = t >> 2, kof = (t & 3) * 8;
  f32x4 acc[6] = {};
  for (int k0 = 0; k0 < 512; k0 += 32) {
    *(bf16x8*)&lds_a[row * 40 + kof] = *(const bf16x8*)&A[(size_t)(m0 + row) * 512 + k0 + kof];
    for (int idx = t; idx < 384; idx += 256) {
      int r2 = idx >> 2, k2 = (idx & 3) * 8;
      *(bf16x8*)&lds_b[r2 * 40 + k2] = *(const bf16x8*)&B[(size_t)r2 * 512 + k0 + k2];
    }
    __syncthreads();
    bf16x8 af = *(bf16x8*)&lds_a[(wave * 16 + id) * 40 + quad * 8];
#pragma unroll
    for (int j = 0; j < 6; j++) {
      bf16x8 bg = *(bf16x8*)&lds_b[(j * 16 + id) * 40 + quad * 8];
      acc[j] = __builtin_amdgcn_mfma_f32_16x16x32_bf16(af, bg, acc[j], 0, 0, 0);
    }
    __syncthreads();
  }
#pragma unroll
  for (int j = 0; j < 6; j++)
#pragma unroll
    for (int r = 0; r < 4; r++) {
      int e = j * 16 + id;
      int m = m0 + wave * 16 + quad * 4 + r;
      ctxT[((size_t)bh * 96 + e) * 256 + m] = (bf16)acc[j][r];
    }
}

// ---------------- den[bh,n] = sum_m pq[bh,n,m]*ksum[bh,m] ----------------
__global__ __launch_bounds__(256) void den_kernel(const bf16* __restrict__ pq,
    const float* __restrict__ ksum, float* __restrict__ den) {
  int bh = blockIdx.y;
  int wave = threadIdx.x >> 6, lane = threadIdx.x & 63;
  int n = blockIdx.x * 4 + wave;
  const bf16* p = pq + ((size_t)bh * 512 + n) * 256 + lane * 4;
  const float* ks = ksum + bh * 256 + lane * 4;
  bf16x4 pv = *(const bf16x4*)p;
  float s = (float)pv[0] * ks[0] + (float)pv[1] * ks[1] + (float)pv[2] * ks[2] + (float)pv[3] * ks[3];
  s = waveSum(s);
  if (lane == 0) den[bh * 512 + n] = s;
}

// ---------------- out GEMM: attn[b,n,h*96+e] = (sum_m pq[n,m]*ctxT[e,m]) / den[n] ----------------
__global__ __launch_bounds__(256) void out_gemm(const bf16* __restrict__ pq,
    const bf16* __restrict__ ctxT, const float* __restrict__ den, bf16* __restrict__ attn) {
  __shared__ __attribute__((aligned(16))) bf16 lds_a[64 * 40];
  __shared__ __attribute__((aligned(16))) bf16 lds_b[96 * 40];
  const int t = threadIdx.x;
  const int bh = blockIdx.y, m0 = blockIdx.x * 64;
  const int b = bh >> 3, h = bh & 7;
  const bf16* A = pq + (size_t)bh * 512 * 256;
  const bf16* B = ctxT + (size_t)bh * 96 * 256;
  const int wave = t >> 6, lane = t & 63;
  const int quad = lane >> 4, id = lane & 15;
  const int row = t >> 2, kof = (t & 3) * 8;
  f32x4 acc[6] = {};
  for (int k0 = 0; k0 < 256; k0 += 32) {
    *(bf16x8*)&lds_a[row * 40 + kof] = *(const bf16x8*)&A[(size_t)(m0 + row) * 256 + k0 + kof];
    for (int idx = t; idx < 384; idx += 256) {
      int r2 = idx >> 2, k2 = (idx & 3) * 8;
      *(bf16x8*)&lds_b[r2 * 40 + k2] = *(const bf16x8*)&B[(size_t)r2 * 256 + k0 + k2];
    }
    __syncthreads();
    bf16x8 af = *(bf16x8*)&lds_a[(wave * 16 + id) * 40 + quad * 8];
#pragma unroll
    for (int j = 0; j < 6; j++) {
      bf16x8 bg = *(bf16x8*)&lds_b[(j * 16 + id) * 40 + quad * 8];
      acc[j] = __builtin_amdgcn_mfma_f32_16x16x32_bf16(af, bg, acc[j], 0, 0, 0);
    }
    __syncthreads();
  }
#pragma unroll
  for (int j = 0; j < 6; j++)
#pragma unroll
    for (int r = 0; r < 4; r++) {
      int e = j * 16 + id;
      int n = m0 + wave * 16 + quad * 4 + r;
      float v = acc[j][r] / fmaxf(den[bh * 512 + n], 1e-30f);
      attn[((size_t)(b * 512 + n)) * 768 + h * 96 + e] = (bf16)v;
    }
}

// ---------------- final head: out[b,j,n] = sigmoid(x_row . mask_w[:,j] + mask_b[j]) (f32 out) ----------------
__global__ __launch_bounds__(256) void mask_kernel(const float* __restrict__ x,
    const float* __restrict__ mw, const float* __restrict__ mb, float* __restrict__ out) {
  int row = blockIdx.x * 4 + (threadIdx.x >> 6);   // 0..4095
  int lane = threadIdx.x & 63;
  int b = row >> 9, n = row & 511;
  const float* xr = x + (size_t)row * 768;
  float a0 = 0, a1 = 0, a2 = 0, a3 = 0;
  for (int d = lane; d < 768; d += 64) {
    float xv = xr[d];
    a0 += xv * mw[d * 4 + 0];
    a1 += xv * mw[d * 4 + 1];
    a2 += xv * mw[d * 4 + 2];
    a3 += xv * mw[d * 4 + 3];
  }
  a0 = waveSum(a0); a1 = waveSum(a1); a2 = waveSum(a2); a3 = waveSum(a3);
  if (lane == 0) {
    out[((size_t)b * 4 + 0) * 512 + n] = 1.f / (1.f + expf(-(a0 + mb[0])));
    out[((size_t)b * 4 + 1) * 512 + n] = 1.f / (1.f + expf(-(a1 + mb[1])));
    out[((size_t)b * 4 + 2) * 512 + n] = 1.f / (1.f + expf(-(a2 + mb[2])));
    out[((size_t)b * 4 + 3) * 512 + n] = 1.f / (1.f + expf(-(a3 + mb[3])));
  }
}

extern "C" void kernel_launch(void* const* d_in, const int* in_sizes, int n_in,
                              void* d_out, int out_size, void* d_ws, size_t ws_size,
                              hipStream_t stream) {
  const float* mel     = (const float*)d_in[0];
  const float* patch_w = (const float*)d_in[1];
  const float* patch_b = (const float*)d_in[2];
  const float* pos     = (const float*)d_in[3];
  const float* proj    = (const float*)d_in[4];
  const float* ln1_s   = (const float*)d_in[5];
  const float* ln1_b   = (const float*)d_in[6];
  const float* qkv_w   = (const float*)d_in[7];
  const float* qkv_b   = (const float*)d_in[8];
  const float* ao_w    = (const float*)d_in[9];
  const float* ao_b    = (const float*)d_in[10];
  const float* ln2_s   = (const float*)d_in[11];
  const float* ln2_b   = (const float*)d_in[12];
  const float* ff1_w   = (const float*)d_in[13];
  const float* ff1_b   = (const float*)d_in[14];
  const float* ff2_w   = (const float*)d_in[15];
  const float* ff2_b   = (const float*)d_in[16];
  const float* mask_w  = (const float*)d_in[17];
  const float* mask_b  = (const float*)d_in[18];

  char* ws = (char*)d_ws;
  size_t off = 0;
  auto alloc = [&](size_t bytes) { void* p = ws + off; off += (bytes + 255) & ~(size_t)255; return p; };
  float* x    = (float*)alloc(4096ull * 768 * 4);
  bf16* h     = (bf16*)alloc(4096ull * 768 * 2);
  bf16* qkv   = (bf16*)alloc(4096ull * 2304 * 2);
  bf16* wtq   = (bf16*)alloc(2304ull * 768 * 2);
  bf16* wta   = (bf16*)alloc(768ull * 768 * 2);
  bf16* wtf1  = (bf16*)alloc(3072ull * 768 * 2);
  bf16* wtf2  = (bf16*)alloc(768ull * 3072 * 2);
  float* u    = (float*)alloc(8388608ull * 4);
  bf16* ffh   = (bf16*)u;  // alias: ffh (25.2MB) fits in u (33.5MB); disjoint lifetimes
  float* diag = (float*)alloc(65536ull * 4);
  bf16* pq    = (bf16*)alloc(8388608ull * 2);
  bf16* pk    = (bf16*)alloc(8388608ull * 2);
  bf16* pkT   = (bf16*)alloc(8388608ull * 2);
  bf16* vT    = (bf16*)alloc(64ull * 96 * 512 * 2);
  bf16* ctxT  = (bf16*)alloc(64ull * 96 * 256 * 2);
  float* ksum = (float*)alloc(64ull * 256 * 4);
  float* den  = (float*)alloc(64ull * 512 * 4);
  float* bmax = (float*)alloc(2048ull * 4);
  float* kmx  = (float*)alloc(256);
  bf16* attn  = (bf16*)alloc(4096ull * 768 * 2);
  bf16* projb = (bf16*)alloc(256ull * 96 * 2);
  if (ws_size < off) return;  // clean fail instead of corruption

  patch_kernel<<<4096, 256, 0, stream>>>(mel, patch_w, patch_b, pos, x);
  cvt_kernel<<<96, 256, 0, stream>>>(proj, projb, 24576);

  for (int l = 0; l < 6; l++) {
    transpose_cvt_kernel<<<dim3(36, 12, 1), 256, 0, stream>>>(qkv_w + (size_t)l * 768 * 2304, wtq, 768, 2304);
    transpose_cvt_kernel<<<dim3(12, 12, 1), 256, 0, stream>>>(ao_w + (size_t)l * 768 * 768, wta, 768, 768);
    transpose_cvt_kernel<<<dim3(48, 12, 1), 256, 0, stream>>>(ff1_w + (size_t)l * 768 * 3072, wtf1, 768, 3072);
    transpose_cvt_kernel<<<dim3(12, 48, 1), 256, 0, stream>>>(ff2_w + (size_t)l * 3072 * 768, wtf2, 3072, 768);

    ln_kernel<<<4096, 256, 0, stream>>>(x, ln1_s + l * 768, ln1_b + l * 768, h);
    gemm128<<<dim3(32, 18), 256, 0, stream>>>(h, wtq, qkv_b + l * 2304, qkv, nullptr, nullptr, 4096, 2304, 768, 0);

    diag_kernel<<<16384, 256, 0, stream>>>(qkv, diag);
    phi_u_gemm<<<dim3(4, 2, 64), 256, 0, stream>>>(qkv, projb, u, 0);
    pq_kernel<<<32768, 256, 0, stream>>>(u, diag, pq);
    phi_u_gemm<<<dim3(4, 2, 64), 256, 0, stream>>>(qkv, projb, u, 1);
    kmax1_kernel<<<2048, 256, 0, stream>>>(u, bmax);
    kmax2_kernel<<<1, 256, 0, stream>>>(bmax, kmx);
    pk_kernel<<<32768, 256, 0, stream>>>(u, diag + 32768, kmx, pk);
    transpose_bf_kernel<<<dim3(4, 8, 64), 256, 0, stream>>>(pk, pkT, 512, 256);
    ksum_kernel<<<64, 256, 0, stream>>>(pk, ksum);
    vt_kernel<<<dim3(8, 64), 256, 0, stream>>>(qkv, vT);
    ctx_gemm<<<dim3(4, 64), 256, 0, stream>>>(pkT, vT, ctxT);
    den_kernel<<<dim3(128, 64), 256, 0, stream>>>(pq, ksum, den);
    out_gemm<<<dim3(8, 64), 256, 0, stream>>>(pq, ctxT, den, attn);
    gemm128<<<dim3(32, 6), 256, 0, stream>>>(attn, wta, ao_b + l * 768, nullptr, x, x, 4096, 768, 768, 2);

    ln_kernel<<<4096, 256, 0, stream>>>(x, ln2_s + l * 768, ln2_b + l * 768, h);
    gemm128<<<dim3(32, 24), 256, 0, stream>>>(h, wtf1, ff1_b + l * 3072, ffh, nullptr, nullptr, 4096, 3072, 768, 1);
    gemm128<<<dim3(32, 6), 256, 0, stream>>>(ffh, wtf2, ff2_b + l * 768, nullptr, x, x, 4096, 768, 3072, 2);
  }

  mask_kernel<<<1024, 256, 0, stream>>>(x, mask_w, mask_b, (float*)d_out);
}

// Round 3
// 2008.930 us; speedup vs baseline: 1.3642x; 1.3642x over previous
//
#include <hip/hip_runtime.h>
#include <hip/hip_bf16.h>

typedef __bf16 bf16;
typedef __bf16 bf16x8 __attribute__((ext_vector_type(8)));
typedef float f32x4 __attribute__((ext_vector_type(4)));
typedef unsigned int u32;

#define PHI_SCALE  0.31947154f   // 96^-0.25
#define DIAG_SCALE 0.05103104f   // 0.5 * 96^-0.5
#define FEAT_SCALE 0.0625f       // 256^-0.5

// async global->LDS, 16B per lane; LDS dest = wave-uniform base + lane*16
__device__ __forceinline__ void glds16(const bf16* g, bf16* l) {
  __builtin_amdgcn_global_load_lds(
      (const __attribute__((address_space(1))) u32*)g,
      (__attribute__((address_space(3))) u32*)l, 16, 0, 0);
}

// ---------------- reductions ----------------
__device__ __forceinline__ float waveSum(float v) {
#pragma unroll
  for (int o = 32; o > 0; o >>= 1) v += __shfl_xor(v, o, 64);
  return v;
}
__device__ __forceinline__ float waveMax(float v) {
#pragma unroll
  for (int o = 32; o > 0; o >>= 1) v = fmaxf(v, __shfl_xor(v, o, 64));
  return v;
}
__device__ __forceinline__ float blockSum(float v) {
  __shared__ float tmp[4];
  v = waveSum(v);
  if ((threadIdx.x & 63) == 0) tmp[threadIdx.x >> 6] = v;
  __syncthreads();
  float r = tmp[0] + tmp[1] + tmp[2] + tmp[3];
  __syncthreads();
  return r;
}
__device__ __forceinline__ float blockMax(float v) {
  __shared__ float tmp[4];
  v = waveMax(v);
  if ((threadIdx.x & 63) == 0) tmp[threadIdx.x >> 6] = v;
  __syncthreads();
  float r = fmaxf(fmaxf(tmp[0], tmp[1]), fmaxf(tmp[2], tmp[3]));
  __syncthreads();
  return r;
}

// ---------------- patch gather: mel f32 -> patches bf16 (4096 x 256) ----------------
__global__ __launch_bounds__(256) void patches_kernel(const float* __restrict__ mel,
    bf16* __restrict__ patches) {
  int blk = blockIdx.x, t = threadIdx.x;
  int b = blk >> 9, n = blk & 511;
  int r0 = (n >> 3) << 4, c0 = (n & 7) << 4;
  patches[(size_t)blk * 256 + t] =
      (bf16)mel[((size_t)b * 1024 + r0 + (t >> 4)) * 128 + c0 + (t & 15)];
}

// ---------------- f32 -> bf16 convert ----------------
__global__ __launch_bounds__(256) void cvt_kernel(const float* __restrict__ src,
    bf16* __restrict__ dst, int n) {
  int i = blockIdx.x * 256 + threadIdx.x;
  if (i < n) dst[i] = (bf16)src[i];
}

// ---------------- transpose + convert: src f32 (K x N) -> dst bf16 (N x K) ----------------
__global__ __launch_bounds__(256) void transpose_cvt_kernel(const float* __restrict__ src,
    bf16* __restrict__ dst, int K, int N) {
  __shared__ float lds[64][65];
  int n0 = blockIdx.x * 64, k0 = blockIdx.y * 64;
  int t = threadIdx.x;
  for (int idx = t; idx < 4096; idx += 256) {
    int r = idx >> 6, c = idx & 63;
    lds[r][c] = src[(size_t)(k0 + r) * N + n0 + c];
  }
  __syncthreads();
  for (int idx = t; idx < 4096; idx += 256) {
    int r = idx >> 6, c = idx & 63;
    dst[(size_t)(n0 + r) * K + k0 + c] = (bf16)lds[c][r];
  }
}

// ---------------- layernorm: x(f32, rows x 768) -> h(bf16) ----------------
__global__ __launch_bounds__(256) void ln_kernel(const float* __restrict__ x,
    const float* __restrict__ s, const float* __restrict__ bta, bf16* __restrict__ h) {
  int row = blockIdx.x;
  const float* xr = x + (size_t)row * 768;
  int t = threadIdx.x;
  float v0 = xr[t], v1 = xr[t + 256], v2 = xr[t + 512];
  float mu = blockSum(v0 + v1 + v2) * (1.f / 768.f);
  float d0 = v0 - mu, d1 = v1 - mu, d2 = v2 - mu;
  float var = blockSum(d0 * d0 + d1 * d1 + d2 * d2) * (1.f / 768.f);
  float inv = rsqrtf(var + 1e-5f);
  bf16* hr = h + (size_t)row * 768;
  hr[t]       = (bf16)(d0 * inv * s[t]       + bta[t]);
  hr[t + 256] = (bf16)(d1 * inv * s[t + 256] + bta[t + 256]);
  hr[t + 512] = (bf16)(d2 * inv * s[t + 512] + bta[t + 512]);
}

// ---------------- main 128x128 MFMA GEMM, global_load_lds staging (m97 structure) ------
// C(MxN) = A(MxK,row bf16) @ B(NxK,row bf16)^T
// mode 0: outb=bf16(acc+bias); 1: outb=bf16(gelu(acc+bias)); 2: xout=xin+acc+bias;
// mode 3: xout = acc + bias + pos[(rr&511)*768+cc]
__global__ __launch_bounds__(256) void gemm128(const bf16* __restrict__ A,
    const bf16* __restrict__ B, const float* __restrict__ bias,
    bf16* __restrict__ outb, const float* __restrict__ xin, float* __restrict__ xout,
    const float* __restrict__ pos, int N, int K, int mode) {
  __shared__ __attribute__((aligned(16))) bf16 lds_a[128 * 32];
  __shared__ __attribute__((aligned(16))) bf16 lds_b[128 * 32];
  const int t = threadIdx.x;
  const int m0 = blockIdx.x * 128, n0 = blockIdx.y * 128;
  const int wave = t >> 6, lane = t & 63;
  const int quad = lane >> 4, id = lane & 15;
  const int wr = (wave >> 1) * 64, wc = (wave & 1) * 64;
  const int srow = wave * 32 + (lane >> 2);   // wave-call rows: 16 rows per 1KB call
  const int scol = (lane & 3) * 8;
  const bf16* pa0 = A + (size_t)(m0 + srow) * K + scol;
  const bf16* pa1 = pa0 + (size_t)16 * K;
  const bf16* pb0 = B + (size_t)(n0 + srow) * K + scol;
  const bf16* pb1 = pb0 + (size_t)16 * K;
  bf16* la0 = lds_a + wave * 1024;
  bf16* la1 = la0 + 512;
  bf16* lb0 = lds_b + wave * 1024;
  bf16* lb1 = lb0 + 512;
  f32x4 acc[4][4] = {};
  for (int k0 = 0; k0 < K; k0 += 32) {
    glds16(pa0, la0); glds16(pa1, la1);
    glds16(pb0, lb0); glds16(pb1, lb1);
    pa0 += 32; pa1 += 32; pb0 += 32; pb1 += 32;
    __syncthreads();
    bf16x8 af[4], bg[4];
#pragma unroll
    for (int i = 0; i < 4; i++) af[i] = *(bf16x8*)&lds_a[(wr + i * 16 + id) * 32 + quad * 8];
#pragma unroll
    for (int j = 0; j < 4; j++) bg[j] = *(bf16x8*)&lds_b[(wc + j * 16 + id) * 32 + quad * 8];
#pragma unroll
    for (int i = 0; i < 4; i++)
#pragma unroll
      for (int j = 0; j < 4; j++)
        acc[i][j] = __builtin_amdgcn_mfma_f32_16x16x32_bf16(af[i], bg[j], acc[i][j], 0, 0, 0);
    __syncthreads();
  }
#pragma unroll
  for (int i = 0; i < 4; i++) {
#pragma unroll
    for (int j = 0; j < 4; j++) {
#pragma unroll
      for (int r = 0; r < 4; r++) {
        int rr = m0 + wr + i * 16 + quad * 4 + r;
        int cc = n0 + wc + j * 16 + id;
        float v = acc[i][j][r] + bias[cc];
        if (mode == 0) {
          outb[(size_t)rr * N + cc] = (bf16)v;
        } else if (mode == 1) {
          outb[(size_t)rr * N + cc] = (bf16)(0.5f * v * (1.0f + erff(v * 0.70710678f)));
        } else if (mode == 2) {
          xout[(size_t)rr * N + cc] = xin[(size_t)rr * N + cc] + v;
        } else {
          xout[(size_t)rr * N + cc] = v + pos[(size_t)(rr & 511) * 768 + cc];
        }
      }
    }
  }
}

// ---------------- fused phi_q: u=qs@proj^T, diag from sumsq, row-max, exp -> pq bf16 ----
// tile 64 n-rows x 256 features, K=96; grid (8 ntiles, 64 bh)
__global__ __launch_bounds__(256) void phi_q_kernel(const bf16* __restrict__ qkv,
    const bf16* __restrict__ proj, bf16* __restrict__ pq) {
  __shared__ __attribute__((aligned(16))) bf16 lA[3][64 * 32];
  __shared__ __attribute__((aligned(16))) bf16 lB[3][256 * 32];
  __shared__ float sqlds[64];
  const int t = threadIdx.x;
  const int nt = blockIdx.x, bh = blockIdx.y;
  const int b = bh >> 3, h = bh & 7;
  const int n0 = nt * 64;
  const bf16* Abase = qkv + ((size_t)(b * 512 + n0)) * 2304 + h * 96;
#pragma unroll
  for (int c = 0; c < 3; c++) {
    int v = c * 256 + t;
    int row = v / 12, s = v % 12;
    *(bf16x8*)&lA[s >> 2][row * 32 + (s & 3) * 8] = *(const bf16x8*)&Abase[(size_t)row * 2304 + s * 8];
  }
#pragma unroll
  for (int c = 0; c < 12; c++) {
    int v = c * 256 + t;
    int row = v / 12, s = v % 12;
    *(bf16x8*)&lB[s >> 2][row * 32 + (s & 3) * 8] = *(const bf16x8*)&proj[(size_t)row * 96 + s * 8];
  }
  __syncthreads();
  const int wave = t >> 6, lane = t & 63, quad = lane >> 4, id = lane & 15;
  f32x4 acc[16] = {};
  float sq = 0.f;
#pragma unroll
  for (int kb = 0; kb < 3; kb++) {
    bf16x8 af = *(bf16x8*)&lA[kb][(wave * 16 + id) * 32 + quad * 8];
#pragma unroll
    for (int e = 0; e < 8; e++) { float fv = (float)af[e]; sq += fv * fv; }
#pragma unroll
    for (int j = 0; j < 16; j++) {
      bf16x8 bg = *(bf16x8*)&lB[kb][(j * 16 + id) * 32 + quad * 8];
      acc[j] = __builtin_amdgcn_mfma_f32_16x16x32_bf16(af, bg, acc[j], 0, 0, 0);
    }
  }
  sq += __shfl_xor(sq, 16, 64);
  sq += __shfl_xor(sq, 32, 64);
  if (quad == 0) sqlds[wave * 16 + id] = sq;
  __syncthreads();
#pragma unroll
  for (int r = 0; r < 4; r++) {
    int rrow = quad * 4 + r;
    float dg = DIAG_SCALE * sqlds[wave * 16 + rrow];
    float mx = -1e30f;
#pragma unroll
    for (int j = 0; j < 16; j++) mx = fmaxf(mx, acc[j][r]);
    mx = fmaxf(mx, __shfl_xor(mx, 1, 64));
    mx = fmaxf(mx, __shfl_xor(mx, 2, 64));
    mx = fmaxf(mx, __shfl_xor(mx, 4, 64));
    mx = fmaxf(mx, __shfl_xor(mx, 8, 64));
    float umax = mx * PHI_SCALE;
#pragma unroll
    for (int j = 0; j < 16; j++) {
      float uu = acc[j][r] * PHI_SCALE;
      float val = (expf(uu - dg - umax) + 1e-4f) * FEAT_SCALE;
      pq[((size_t)bh * 512 + n0 + wave * 16 + rrow) * 256 + j * 16 + id] = (bf16)val;
    }
  }
}

// ---------------- fused phi_k: u, diag, block-max; prov=exp(u-diag-blkmax) bf16 --------
__global__ __launch_bounds__(256) void phi_k_kernel(const bf16* __restrict__ qkv,
    const bf16* __restrict__ proj, bf16* __restrict__ prov, float* __restrict__ kbm) {
  __shared__ __attribute__((aligned(16))) bf16 lA[3][64 * 32];
  __shared__ __attribute__((aligned(16))) bf16 lB[3][256 * 32];
  __shared__ float sqlds[64];
  __shared__ float bmax4[4];
  const int t = threadIdx.x;
  const int nt = blockIdx.x, bh = blockIdx.y;
  const int b = bh >> 3, h = bh & 7;
  const int n0 = nt * 64;
  const bf16* Abase = qkv + ((size_t)(b * 512 + n0)) * 2304 + 768 + h * 96;
#pragma unroll
  for (int c = 0; c < 3; c++) {
    int v = c * 256 + t;
    int row = v / 12, s = v % 12;
    *(bf16x8*)&lA[s >> 2][row * 32 + (s & 3) * 8] = *(const bf16x8*)&Abase[(size_t)row * 2304 + s * 8];
  }
#pragma unroll
  for (int c = 0; c < 12; c++) {
    int v = c * 256 + t;
    int row = v / 12, s = v % 12;
    *(bf16x8*)&lB[s >> 2][row * 32 + (s & 3) * 8] = *(const bf16x8*)&proj[(size_t)row * 96 + s * 8];
  }
  __syncthreads();
  const int wave = t >> 6, lane = t & 63, quad = lane >> 4, id = lane & 15;
  f32x4 acc[16] = {};
  float sq = 0.f;
#pragma unroll
  for (int kb = 0; kb < 3; kb++) {
    bf16x8 af = *(bf16x8*)&lA[kb][(wave * 16 + id) * 32 + quad * 8];
#pragma unroll
    for (int e = 0; e < 8; e++) { float fv = (float)af[e]; sq += fv * fv; }
#pragma unroll
    for (int j = 0; j < 16; j++) {
      bf16x8 bg = *(bf16x8*)&lB[kb][(j * 16 + id) * 32 + quad * 8];
      acc[j] = __builtin_amdgcn_mfma_f32_16x16x32_bf16(af, bg, acc[j], 0, 0, 0);
    }
  }
  sq += __shfl_xor(sq, 16, 64);
  sq += __shfl_xor(sq, 32, 64);
  if (quad == 0) sqlds[wave * 16 + id] = sq;
  float bm = -1e30f;
#pragma unroll
  for (int j = 0; j < 16; j++)
#pragma unroll
    for (int r = 0; r < 4; r++) bm = fmaxf(bm, acc[j][r]);
  bm = waveMax(bm);
  if (lane == 0) bmax4[wave] = bm;
  __syncthreads();
  float blkmax = fmaxf(fmaxf(bmax4[0], bmax4[1]), fmaxf(bmax4[2], bmax4[3])) * PHI_SCALE;
  if (t == 0) kbm[bh * 8 + nt] = blkmax;
#pragma unroll
  for (int r = 0; r < 4; r++) {
    int rrow = quad * 4 + r;
    float dg = DIAG_SCALE * sqlds[wave * 16 + rrow];
#pragma unroll
    for (int j = 0; j < 16; j++) {
      float uu = acc[j][r] * PHI_SCALE;
      prov[((size_t)bh * 512 + n0 + wave * 16 + rrow) * 256 + j * 16 + id] =
          (bf16)expf(uu - dg - blkmax);
    }
  }
}

// ---------------- global max over kbm[512] ----------------
__global__ __launch_bounds__(256) void kred_kernel(const float* __restrict__ kbm,
    float* __restrict__ gmax) {
  int t = threadIdx.x;
  float m = fmaxf(kbm[t], kbm[t + 256]);
  m = blockMax(m);
  if (t == 0) gmax[0] = m;
}

// ---------------- pkT: rescale prov by exp(blkmax-gmax), +1e-4, scale; transpose -------
// grid (4 mtiles, 8 ntiles, 64 bh)
__global__ __launch_bounds__(256) void pkt_kernel(const bf16* __restrict__ prov,
    const float* __restrict__ kbm, const float* __restrict__ gmax, bf16* __restrict__ pkT) {
  __shared__ bf16 lds[64][65];
  const int m0 = blockIdx.x * 64, nt = blockIdx.y, bh = blockIdx.z;
  const int n0 = nt * 64;
  const int t = threadIdx.x;
  float factor = expf(kbm[bh * 8 + nt] - gmax[0]);
  const bf16* src = prov + ((size_t)bh * 512 + n0) * 256 + m0;
#pragma unroll
  for (int c = 0; c < 16; c++) {
    int idx = c * 256 + t; int r = idx >> 6, cc = idx & 63;
    float pv = (float)src[(size_t)r * 256 + cc];
    lds[cc][r] = (bf16)((pv * factor + 1e-4f) * FEAT_SCALE);
  }
  __syncthreads();
  bf16* dst = pkT + ((size_t)bh * 256 + m0) * 512 + n0;
#pragma unroll
  for (int c = 0; c < 16; c++) {
    int idx = c * 256 + t; int r = idx >> 6, cc = idx & 63;
    dst[(size_t)r * 512 + cc] = lds[r][cc];
  }
}

// ---------------- vT[bh,e,n] = qkv[b,n,1536+h*96+e] ----------------
__global__ __launch_bounds__(256) void vt_kernel(const bf16* __restrict__ qkv, bf16* __restrict__ vT) {
  __shared__ bf16 lds[64][97];
  int bh = blockIdx.y, b = bh >> 3, h = bh & 7;
  int n0 = blockIdx.x * 64;
  int t = threadIdx.x;
  const bf16* src = qkv + ((size_t)b * 512 + n0) * 2304 + 1536 + h * 96;
  for (int idx = t; idx < 6144; idx += 256) {
    int r = idx / 96, c = idx % 96;
    lds[r][c] = src[(size_t)r * 2304 + c];
  }
  __syncthreads();
  bf16* dst = vT + (size_t)bh * 96 * 512 + n0;
  for (int idx = t; idx < 6144; idx += 256) {
    int e = idx >> 6, nn = idx & 63;
    dst[(size_t)e * 512 + nn] = lds[nn][e];
  }
}

// ---------------- ctx GEMM + fused ksum: ctxT[bh,e,m], ksum[bh,m]=sum_n pkT[m,n] -------
__global__ __launch_bounds__(256) void ctx_gemm(const bf16* __restrict__ pkT,
    const bf16* __restrict__ vT, bf16* __restrict__ ctxT, float* __restrict__ ksum) {
  __shared__ __attribute__((aligned(16))) bf16 lds_a[64 * 40];
  __shared__ __attribute__((aligned(16))) bf16 lds_b[96 * 40];
  const int t = threadIdx.x;
  const int bh = blockIdx.y, m0 = blockIdx.x * 64;
  const bf16* A = pkT + (size_t)bh * 256 * 512;
  const bf16* B = vT + (size_t)bh * 96 * 512;
  const int wave = t >> 6, lane = t & 63;
  const int quad = lane >> 4, id = lane & 15;
  const int row = t >> 2, kof = (t & 3) * 8;
  f32x4 acc[6] = {};
  float ks = 0.f;
  for (int k0 = 0; k0 < 512; k0 += 32) {
    *(bf16x8*)&lds_a[row * 40 + kof] = *(const bf16x8*)&A[(size_t)(m0 + row) * 512 + k0 + kof];
    for (int idx = t; idx < 384; idx += 256) {
      int r2 = idx >> 2, k2 = (idx & 3) * 8;
      *(bf16x8*)&lds_b[r2 * 40 + k2] = *(const bf16x8*)&B[(size_t)r2 * 512 + k0 + k2];
    }
    __syncthreads();
    bf16x8 af = *(bf16x8*)&lds_a[(wave * 16 + id) * 40 + quad * 8];
#pragma unroll
    for (int e = 0; e < 8; e++) ks += (float)af[e];
#pragma unroll
    for (int j = 0; j < 6; j++) {
      bf16x8 bg = *(bf16x8*)&lds_b[(j * 16 + id) * 40 + quad * 8];
      acc[j] = __builtin_amdgcn_mfma_f32_16x16x32_bf16(af, bg, acc[j], 0, 0, 0);
    }
    __syncthreads();
  }
  ks += __shfl_xor(ks, 16, 64);
  ks += __shfl_xor(ks, 32, 64);
  if (quad == 0) ksum[bh * 256 + m0 + wave * 16 + id] = ks;
#pragma unroll
  for (int j = 0; j < 6; j++)
#pragma unroll
    for (int r = 0; r < 4; r++) {
      int e = j * 16 + id;
      int m = m0 + wave * 16 + quad * 4 + r;
      ctxT[((size_t)bh * 96 + e) * 256 + m] = (bf16)acc[j][r];
    }
}

// ---------------- out GEMM + fused den: attn = (pq @ ctxT^T) / (pq . ksum) -------------
__global__ __launch_bounds__(256) void out_gemm(const bf16* __restrict__ pq,
    const bf16* __restrict__ ctxT, const float* __restrict__ ksum, bf16* __restrict__ attn) {
  __shared__ __attribute__((aligned(16))) bf16 lds_a[64 * 40];
  __shared__ __attribute__((aligned(16))) bf16 lds_b[96 * 40];
  __shared__ float den_lds[64];
  const int t = threadIdx.x;
  const int bh = blockIdx.y, m0 = blockIdx.x * 64;
  const int b = bh >> 3, h = bh & 7;
  const bf16* A = pq + (size_t)bh * 512 * 256;
  const bf16* B = ctxT + (size_t)bh * 96 * 256;
  const int wave = t >> 6, lane = t & 63;
  const int quad = lane >> 4, id = lane & 15;
  const int row = t >> 2, kof = (t & 3) * 8;
  f32x4 acc[6] = {};
  float den = 0.f;
  for (int k0 = 0; k0 < 256; k0 += 32) {
    *(bf16x8*)&lds_a[row * 40 + kof] = *(const bf16x8*)&A[(size_t)(m0 + row) * 256 + k0 + kof];
    for (int idx = t; idx < 384; idx += 256) {
      int r2 = idx >> 2, k2 = (idx & 3) * 8;
      *(bf16x8*)&lds_b[r2 * 40 + k2] = *(const bf16x8*)&B[(size_t)r2 * 256 + k0 + k2];
    }
    __syncthreads();
    bf16x8 af = *(bf16x8*)&lds_a[(wave * 16 + id) * 40 + quad * 8];
    const f32x4* kp = (const f32x4*)(ksum + bh * 256 + k0 + quad * 8);
    f32x4 k0v = kp[0], k1v = kp[1];
#pragma unroll
    for (int e = 0; e < 4; e++) den += (float)af[e] * k0v[e];
#pragma unroll
    for (int e = 0; e < 4; e++) den += (float)af[e + 4] * k1v[e];
#pragma unroll
    for (int j = 0; j < 6; j++) {
      bf16x8 bg = *(bf16x8*)&lds_b[(j * 16 + id) * 40 + quad * 8];
      acc[j] = __builtin_amdgcn_mfma_f32_16x16x32_bf16(af, bg, acc[j], 0, 0, 0);
    }
    __syncthreads();
  }
  den += __shfl_xor(den, 16, 64);
  den += __shfl_xor(den, 32, 64);
  if (quad == 0) den_lds[wave * 16 + id] = den;
  __syncthreads();
#pragma unroll
  for (int j = 0; j < 6; j++)
#pragma unroll
    for (int r = 0; r < 4; r++) {
      int e = j * 16 + id;
      int n = m0 + wave * 16 + quad * 4 + r;
      float v = acc[j][r] / fmaxf(den_lds[wave * 16 + quad * 4 + r], 1e-30f);
      attn[((size_t)(b * 512 + n)) * 768 + h * 96 + e] = (bf16)v;
    }
}

// ---------------- final head ----------------
__global__ __launch_bounds__(256) void mask_kernel(const float* __restrict__ x,
    const float* __restrict__ mw, const float* __restrict__ mb, float* __restrict__ out) {
  int row = blockIdx.x * 4 + (threadIdx.x >> 6);
  int lane = threadIdx.x & 63;
  int b = row >> 9, n = row & 511;
  const float* xr = x + (size_t)row * 768;
  float a0 = 0, a1 = 0, a2 = 0, a3 = 0;
  for (int d = lane; d < 768; d += 64) {
    float xv = xr[d];
    a0 += xv * mw[d * 4 + 0];
    a1 += xv * mw[d * 4 + 1];
    a2 += xv * mw[d * 4 + 2];
    a3 += xv * mw[d * 4 + 3];
  }
  a0 = waveSum(a0); a1 = waveSum(a1); a2 = waveSum(a2); a3 = waveSum(a3);
  if (lane == 0) {
    out[((size_t)b * 4 + 0) * 512 + n] = 1.f / (1.f + expf(-(a0 + mb[0])));
    out[((size_t)b * 4 + 1) * 512 + n] = 1.f / (1.f + expf(-(a1 + mb[1])));
    out[((size_t)b * 4 + 2) * 512 + n] = 1.f / (1.f + expf(-(a2 + mb[2])));
    out[((size_t)b * 4 + 3) * 512 + n] = 1.f / (1.f + expf(-(a3 + mb[3])));
  }
}

extern "C" void kernel_launch(void* const* d_in, const int* in_sizes, int n_in,
                              void* d_out, int out_size, void* d_ws, size_t ws_size,
                              hipStream_t stream) {
  const float* mel     = (const float*)d_in[0];
  const float* patch_w = (const float*)d_in[1];
  const float* patch_b = (const float*)d_in[2];
  const float* pos     = (const float*)d_in[3];
  const float* proj    = (const float*)d_in[4];
  const float* ln1_s   = (const float*)d_in[5];
  const float* ln1_b   = (const float*)d_in[6];
  const float* qkv_w   = (const float*)d_in[7];
  const float* qkv_b   = (const float*)d_in[8];
  const float* ao_w    = (const float*)d_in[9];
  const float* ao_b    = (const float*)d_in[10];
  const float* ln2_s   = (const float*)d_in[11];
  const float* ln2_b   = (const float*)d_in[12];
  const float* ff1_w   = (const float*)d_in[13];
  const float* ff1_b   = (const float*)d_in[14];
  const float* ff2_w   = (const float*)d_in[15];
  const float* ff2_b   = (const float*)d_in[16];
  const float* mask_w  = (const float*)d_in[17];
  const float* mask_b  = (const float*)d_in[18];

  char* ws = (char*)d_ws;
  size_t off = 0;
  auto alloc = [&](size_t bytes) { void* p = ws + off; off += (bytes + 255) & ~(size_t)255; return p; };
  float* x     = (float*)alloc(4096ull * 768 * 4);
  bf16* h      = (bf16*)alloc(4096ull * 768 * 2);
  bf16* qkv    = (bf16*)alloc(4096ull * 2304 * 2);
  bf16* wtq    = (bf16*)alloc(2304ull * 768 * 2);
  bf16* wta    = (bf16*)alloc(768ull * 768 * 2);
  bf16* wtf1   = (bf16*)alloc(3072ull * 768 * 2);
  bf16* wtf2   = (bf16*)alloc(768ull * 3072 * 2);
  bf16* patches= (bf16*)alloc(4096ull * 256 * 2);
  bf16* pwb    = (bf16*)alloc(768ull * 256 * 2);
  bf16* projb  = (bf16*)alloc(256ull * 96 * 2);
  bf16* pq     = (bf16*)alloc(8388608ull * 2);
  bf16* prov   = (bf16*)alloc(8388608ull * 2);
  bf16* pkT    = (bf16*)alloc(8388608ull * 2);
  bf16* vT     = (bf16*)alloc(64ull * 96 * 512 * 2);
  bf16* ctxT   = (bf16*)alloc(64ull * 96 * 256 * 2);
  float* ksum  = (float*)alloc(64ull * 256 * 4);
  float* kbm   = (float*)alloc(512ull * 4);
  float* gmax  = (float*)alloc(256);
  bf16* attn   = (bf16*)alloc(4096ull * 768 * 2);
  bf16* ffh    = (bf16*)alloc(4096ull * 3072 * 2);
  if (ws_size < off) return;  // clean fail instead of corruption

  patches_kernel<<<4096, 256, 0, stream>>>(mel, patches);
  cvt_kernel<<<768, 256, 0, stream>>>(patch_w, pwb, 196608);
  cvt_kernel<<<96, 256, 0, stream>>>(proj, projb, 24576);
  gemm128<<<dim3(32, 6), 256, 0, stream>>>(patches, pwb, patch_b, nullptr, nullptr, x, pos,
                                           768, 256, 3);

  for (int l = 0; l < 6; l++) {
    transpose_cvt_kernel<<<dim3(36, 12), 256, 0, stream>>>(qkv_w + (size_t)l * 768 * 2304, wtq, 768, 2304);
    transpose_cvt_kernel<<<dim3(12, 12), 256, 0, stream>>>(ao_w + (size_t)l * 768 * 768, wta, 768, 768);
    transpose_cvt_kernel<<<dim3(48, 12), 256, 0, stream>>>(ff1_w + (size_t)l * 768 * 3072, wtf1, 768, 3072);
    transpose_cvt_kernel<<<dim3(12, 48), 256, 0, stream>>>(ff2_w + (size_t)l * 3072 * 768, wtf2, 3072, 768);

    ln_kernel<<<4096, 256, 0, stream>>>(x, ln1_s + l * 768, ln1_b + l * 768, h);
    gemm128<<<dim3(32, 18), 256, 0, stream>>>(h, wtq, qkv_b + l * 2304, qkv, nullptr, nullptr,
                                              nullptr, 2304, 768, 0);

    phi_q_kernel<<<dim3(8, 64), 256, 0, stream>>>(qkv, projb, pq);
    phi_k_kernel<<<dim3(8, 64), 256, 0, stream>>>(qkv, projb, prov, kbm);
    kred_kernel<<<1, 256, 0, stream>>>(kbm, gmax);
    pkt_kernel<<<dim3(4, 8, 64), 256, 0, stream>>>(prov, kbm, gmax, pkT);
    vt_kernel<<<dim3(8, 64), 256, 0, stream>>>(qkv, vT);
    ctx_gemm<<<dim3(4, 64), 256, 0, stream>>>(pkT, vT, ctxT, ksum);
    out_gemm<<<dim3(8, 64), 256, 0, stream>>>(pq, ctxT, ksum, attn);
    gemm128<<<dim3(32, 6), 256, 0, stream>>>(attn, wta, ao_b + l * 768, nullptr, x, x,
                                             nullptr, 768, 768, 2);

    ln_kernel<<<4096, 256, 0, stream>>>(x, ln2_s + l * 768, ln2_b + l * 768, h);
    gemm128<<<dim3(32, 24), 256, 0, stream>>>(h, wtf1, ff1_b + l * 3072, ffh, nullptr, nullptr,
                                              nullptr, 3072, 768, 1);
    gemm128<<<dim3(32, 6), 256, 0, stream>>>(ffh, wtf2, ff2_b + l * 768, nullptr, x, x,
                                             nullptr, 768, 3072, 2);
  }

  mask_kernel<<<1024, 256, 0, stream>>>(x, mask_w, mask_b, (float*)d_out);
}

// Round 4
// 1994.031 us; speedup vs baseline: 1.3744x; 1.0075x over previous
//
#include <hip/hip_runtime.h>
#include <hip/hip_bf16.h>

typedef __bf16 bf16;
typedef __bf16 bf16x8 __attribute__((ext_vector_type(8)));
typedef float f32x4 __attribute__((ext_vector_type(4)));
typedef unsigned int u32;

#define PHI_SCALE  0.31947154f   // 96^-0.25
#define DIAG_SCALE 0.05103104f   // 0.5 * 96^-0.5
#define FEAT_SCALE 0.0625f       // 256^-0.5

// async global->LDS, 16B per lane; LDS dest = wave-uniform base + lane*16
__device__ __forceinline__ void glds16(const bf16* g, bf16* l) {
  __builtin_amdgcn_global_load_lds(
      (const __attribute__((address_space(1))) u32*)g,
      (__attribute__((address_space(3))) u32*)l, 16, 0, 0);
}

// ---------------- reductions ----------------
__device__ __forceinline__ float waveSum(float v) {
#pragma unroll
  for (int o = 32; o > 0; o >>= 1) v += __shfl_xor(v, o, 64);
  return v;
}
__device__ __forceinline__ float waveMax(float v) {
#pragma unroll
  for (int o = 32; o > 0; o >>= 1) v = fmaxf(v, __shfl_xor(v, o, 64));
  return v;
}
__device__ __forceinline__ float blockSum(float v) {
  __shared__ float tmp[4];
  v = waveSum(v);
  if ((threadIdx.x & 63) == 0) tmp[threadIdx.x >> 6] = v;
  __syncthreads();
  float r = tmp[0] + tmp[1] + tmp[2] + tmp[3];
  __syncthreads();
  return r;
}
__device__ __forceinline__ float blockMax(float v) {
  __shared__ float tmp[4];
  v = waveMax(v);
  if ((threadIdx.x & 63) == 0) tmp[threadIdx.x >> 6] = v;
  __syncthreads();
  float r = fmaxf(fmaxf(tmp[0], tmp[1]), fmaxf(tmp[2], tmp[3]));
  __syncthreads();
  return r;
}

// ---------------- patch gather: mel f32 -> patches bf16 (4096 x 256) ----------------
__global__ __launch_bounds__(256) void patches_kernel(const float* __restrict__ mel,
    bf16* __restrict__ patches) {
  int blk = blockIdx.x, t = threadIdx.x;
  int b = blk >> 9, n = blk & 511;
  int r0 = (n >> 3) << 4, c0 = (n & 7) << 4;
  patches[(size_t)blk * 256 + t] =
      (bf16)mel[((size_t)b * 1024 + r0 + (t >> 4)) * 128 + c0 + (t & 15)];
}

// ---------------- f32 -> bf16 convert ----------------
__global__ __launch_bounds__(256) void cvt_kernel(const float* __restrict__ src,
    bf16* __restrict__ dst, int n) {
  int i = blockIdx.x * 256 + threadIdx.x;
  if (i < n) dst[i] = (bf16)src[i];
}

// ---------------- transpose + convert: src f32 (K x N) -> dst bf16 (N x K) ----------------
__global__ __launch_bounds__(256) void transpose_cvt_kernel(const float* __restrict__ src,
    bf16* __restrict__ dst, int K, int N) {
  __shared__ float lds[64][65];
  int n0 = blockIdx.x * 64, k0 = blockIdx.y * 64;
  int t = threadIdx.x;
  for (int idx = t; idx < 4096; idx += 256) {
    int r = idx >> 6, c = idx & 63;
    lds[r][c] = src[(size_t)(k0 + r) * N + n0 + c];
  }
  __syncthreads();
  for (int idx = t; idx < 4096; idx += 256) {
    int r = idx >> 6, c = idx & 63;
    dst[(size_t)(n0 + r) * K + k0 + c] = (bf16)lds[c][r];
  }
}

// ---------------- layernorm: x(f32, rows x 768) -> h(bf16) ----------------
__global__ __launch_bounds__(256) void ln_kernel(const float* __restrict__ x,
    const float* __restrict__ s, const float* __restrict__ bta, bf16* __restrict__ h) {
  int row = blockIdx.x;
  const float* xr = x + (size_t)row * 768;
  int t = threadIdx.x;
  float v0 = xr[t], v1 = xr[t + 256], v2 = xr[t + 512];
  float mu = blockSum(v0 + v1 + v2) * (1.f / 768.f);
  float d0 = v0 - mu, d1 = v1 - mu, d2 = v2 - mu;
  float var = blockSum(d0 * d0 + d1 * d1 + d2 * d2) * (1.f / 768.f);
  float inv = rsqrtf(var + 1e-5f);
  bf16* hr = h + (size_t)row * 768;
  hr[t]       = (bf16)(d0 * inv * s[t]       + bta[t]);
  hr[t + 256] = (bf16)(d1 * inv * s[t + 256] + bta[t + 256]);
  hr[t + 512] = (bf16)(d2 * inv * s[t + 512] + bta[t + 512]);
}

// ---------------- main 128x128 MFMA GEMM, global_load_lds staging (m97 structure) ------
// C(MxN) = A(MxK,row bf16) @ B(NxK,row bf16)^T   (K split across gridDim.z, kchunk each)
// mode 0: outb=bf16(acc+bias); 1: outb=bf16(gelu(acc+bias));
// mode 3: xout = acc + bias + pos[(rr&511)*768+cc]
// mode 4: atomicAdd(xout, acc (+bias if z==0))   -- residual accumulate, split-K safe
__global__ __launch_bounds__(256) void gemm128(const bf16* __restrict__ A,
    const bf16* __restrict__ B, const float* __restrict__ bias,
    bf16* __restrict__ outb, float* __restrict__ xout,
    const float* __restrict__ pos, int N, int kchunk, int mode) {
  __shared__ __attribute__((aligned(16))) bf16 lds_a[128 * 32];
  __shared__ __attribute__((aligned(16))) bf16 lds_b[128 * 32];
  const int t = threadIdx.x;
  const int m0 = blockIdx.x * 128, n0 = blockIdx.y * 128;
  const int kz = blockIdx.z;
  const int k_start = kz * kchunk;
  const int wave = t >> 6, lane = t & 63;
  const int quad = lane >> 4, id = lane & 15;
  const int wr = (wave >> 1) * 64, wc = (wave & 1) * 64;
  const int srow = wave * 32 + (lane >> 2);   // 16 rows per 1KB wave-call
  const int scol = (lane & 3) * 8;
  const int K = kchunk * gridDim.z;
  const bf16* pa0 = A + (size_t)(m0 + srow) * K + k_start + scol;
  const bf16* pa1 = pa0 + (size_t)16 * K;
  const bf16* pb0 = B + (size_t)(n0 + srow) * K + k_start + scol;
  const bf16* pb1 = pb0 + (size_t)16 * K;
  bf16* la0 = lds_a + wave * 1024;
  bf16* la1 = la0 + 512;
  bf16* lb0 = lds_b + wave * 1024;
  bf16* lb1 = lb0 + 512;
  f32x4 acc[4][4] = {};
  for (int k0 = 0; k0 < kchunk; k0 += 32) {
    glds16(pa0, la0); glds16(pa1, la1);
    glds16(pb0, lb0); glds16(pb1, lb1);
    pa0 += 32; pa1 += 32; pb0 += 32; pb1 += 32;
    __syncthreads();
    bf16x8 af[4], bg[4];
#pragma unroll
    for (int i = 0; i < 4; i++) af[i] = *(bf16x8*)&lds_a[(wr + i * 16 + id) * 32 + quad * 8];
#pragma unroll
    for (int j = 0; j < 4; j++) bg[j] = *(bf16x8*)&lds_b[(wc + j * 16 + id) * 32 + quad * 8];
#pragma unroll
    for (int i = 0; i < 4; i++)
#pragma unroll
      for (int j = 0; j < 4; j++)
        acc[i][j] = __builtin_amdgcn_mfma_f32_16x16x32_bf16(af[i], bg[j], acc[i][j], 0, 0, 0);
    __syncthreads();
  }
#pragma unroll
  for (int i = 0; i < 4; i++) {
#pragma unroll
    for (int j = 0; j < 4; j++) {
#pragma unroll
      for (int r = 0; r < 4; r++) {
        int rr = m0 + wr + i * 16 + quad * 4 + r;
        int cc = n0 + wc + j * 16 + id;
        if (mode == 4) {
          float v = acc[i][j][r] + (kz == 0 ? bias[cc] : 0.f);
          atomicAdd(&xout[(size_t)rr * N + cc], v);
        } else {
          float v = acc[i][j][r] + bias[cc];
          if (mode == 0) {
            outb[(size_t)rr * N + cc] = (bf16)v;
          } else if (mode == 1) {
            outb[(size_t)rr * N + cc] = (bf16)(0.5f * v * (1.0f + erff(v * 0.70710678f)));
          } else {
            xout[(size_t)rr * N + cc] = v + pos[(size_t)(rr & 511) * 768 + cc];
          }
        }
      }
    }
  }
}

// ---------------- fused phi_q: u=qs@proj^T, diag from sumsq, row-max, exp -> pq bf16 ----
__global__ __launch_bounds__(256) void phi_q_kernel(const bf16* __restrict__ qkv,
    const bf16* __restrict__ proj, bf16* __restrict__ pq) {
  __shared__ __attribute__((aligned(16))) bf16 lA[3][64 * 32];
  __shared__ __attribute__((aligned(16))) bf16 lB[3][256 * 32];
  __shared__ float sqlds[64];
  const int t = threadIdx.x;
  const int nt = blockIdx.x, bh = blockIdx.y;
  const int b = bh >> 3, h = bh & 7;
  const int n0 = nt * 64;
  const bf16* Abase = qkv + ((size_t)(b * 512 + n0)) * 2304 + h * 96;
#pragma unroll
  for (int c = 0; c < 3; c++) {
    int v = c * 256 + t;
    int row = v / 12, s = v % 12;
    *(bf16x8*)&lA[s >> 2][row * 32 + (s & 3) * 8] = *(const bf16x8*)&Abase[(size_t)row * 2304 + s * 8];
  }
#pragma unroll
  for (int c = 0; c < 12; c++) {
    int v = c * 256 + t;
    int row = v / 12, s = v % 12;
    *(bf16x8*)&lB[s >> 2][row * 32 + (s & 3) * 8] = *(const bf16x8*)&proj[(size_t)row * 96 + s * 8];
  }
  __syncthreads();
  const int wave = t >> 6, lane = t & 63, quad = lane >> 4, id = lane & 15;
  f32x4 acc[16] = {};
  float sq = 0.f;
#pragma unroll
  for (int kb = 0; kb < 3; kb++) {
    bf16x8 af = *(bf16x8*)&lA[kb][(wave * 16 + id) * 32 + quad * 8];
#pragma unroll
    for (int e = 0; e < 8; e++) { float fv = (float)af[e]; sq += fv * fv; }
#pragma unroll
    for (int j = 0; j < 16; j++) {
      bf16x8 bg = *(bf16x8*)&lB[kb][(j * 16 + id) * 32 + quad * 8];
      acc[j] = __builtin_amdgcn_mfma_f32_16x16x32_bf16(af, bg, acc[j], 0, 0, 0);
    }
  }
  sq += __shfl_xor(sq, 16, 64);
  sq += __shfl_xor(sq, 32, 64);
  if (quad == 0) sqlds[wave * 16 + id] = sq;
  __syncthreads();
#pragma unroll
  for (int r = 0; r < 4; r++) {
    int rrow = quad * 4 + r;
    float dg = DIAG_SCALE * sqlds[wave * 16 + rrow];
    float mx = -1e30f;
#pragma unroll
    for (int j = 0; j < 16; j++) mx = fmaxf(mx, acc[j][r]);
    mx = fmaxf(mx, __shfl_xor(mx, 1, 64));
    mx = fmaxf(mx, __shfl_xor(mx, 2, 64));
    mx = fmaxf(mx, __shfl_xor(mx, 4, 64));
    mx = fmaxf(mx, __shfl_xor(mx, 8, 64));
    float umax = mx * PHI_SCALE;
#pragma unroll
    for (int j = 0; j < 16; j++) {
      float uu = acc[j][r] * PHI_SCALE;
      float val = (expf(uu - dg - umax) + 1e-4f) * FEAT_SCALE;
      pq[((size_t)bh * 512 + n0 + wave * 16 + rrow) * 256 + j * 16 + id] = (bf16)val;
    }
  }
}

// ---------------- fused phi_k: u, diag, block-max; prov=exp(u-diag-blkmax) bf16 --------
__global__ __launch_bounds__(256) void phi_k_kernel(const bf16* __restrict__ qkv,
    const bf16* __restrict__ proj, bf16* __restrict__ prov, float* __restrict__ kbm) {
  __shared__ __attribute__((aligned(16))) bf16 lA[3][64 * 32];
  __shared__ __attribute__((aligned(16))) bf16 lB[3][256 * 32];
  __shared__ float sqlds[64];
  __shared__ float bmax4[4];
  const int t = threadIdx.x;
  const int nt = blockIdx.x, bh = blockIdx.y;
  const int b = bh >> 3, h = bh & 7;
  const int n0 = nt * 64;
  const bf16* Abase = qkv + ((size_t)(b * 512 + n0)) * 2304 + 768 + h * 96;
#pragma unroll
  for (int c = 0; c < 3; c++) {
    int v = c * 256 + t;
    int row = v / 12, s = v % 12;
    *(bf16x8*)&lA[s >> 2][row * 32 + (s & 3) * 8] = *(const bf16x8*)&Abase[(size_t)row * 2304 + s * 8];
  }
#pragma unroll
  for (int c = 0; c < 12; c++) {
    int v = c * 256 + t;
    int row = v / 12, s = v % 12;
    *(bf16x8*)&lB[s >> 2][row * 32 + (s & 3) * 8] = *(const bf16x8*)&proj[(size_t)row * 96 + s * 8];
  }
  __syncthreads();
  const int wave = t >> 6, lane = t & 63, quad = lane >> 4, id = lane & 15;
  f32x4 acc[16] = {};
  float sq = 0.f;
#pragma unroll
  for (int kb = 0; kb < 3; kb++) {
    bf16x8 af = *(bf16x8*)&lA[kb][(wave * 16 + id) * 32 + quad * 8];
#pragma unroll
    for (int e = 0; e < 8; e++) { float fv = (float)af[e]; sq += fv * fv; }
#pragma unroll
    for (int j = 0; j < 16; j++) {
      bf16x8 bg = *(bf16x8*)&lB[kb][(j * 16 + id) * 32 + quad * 8];
      acc[j] = __builtin_amdgcn_mfma_f32_16x16x32_bf16(af, bg, acc[j], 0, 0, 0);
    }
  }
  sq += __shfl_xor(sq, 16, 64);
  sq += __shfl_xor(sq, 32, 64);
  if (quad == 0) sqlds[wave * 16 + id] = sq;
  float bm = -1e30f;
#pragma unroll
  for (int j = 0; j < 16; j++)
#pragma unroll
    for (int r = 0; r < 4; r++) bm = fmaxf(bm, acc[j][r]);
  bm = waveMax(bm);
  if (lane == 0) bmax4[wave] = bm;
  __syncthreads();
  float blkmax = fmaxf(fmaxf(bmax4[0], bmax4[1]), fmaxf(bmax4[2], bmax4[3])) * PHI_SCALE;
  if (t == 0) kbm[bh * 8 + nt] = blkmax;
#pragma unroll
  for (int r = 0; r < 4; r++) {
    int rrow = quad * 4 + r;
    float dg = DIAG_SCALE * sqlds[wave * 16 + rrow];
#pragma unroll
    for (int j = 0; j < 16; j++) {
      float uu = acc[j][r] * PHI_SCALE;
      prov[((size_t)bh * 512 + n0 + wave * 16 + rrow) * 256 + j * 16 + id] =
          (bf16)expf(uu - dg - blkmax);
    }
  }
}

// ---------------- global max over kbm[512] ----------------
__global__ __launch_bounds__(256) void kred_kernel(const float* __restrict__ kbm,
    float* __restrict__ gmax) {
  int t = threadIdx.x;
  float m = fmaxf(kbm[t], kbm[t + 256]);
  m = blockMax(m);
  if (t == 0) gmax[0] = m;
}

// ---------------- pkT: rescale prov by exp(blkmax-gmax), +1e-4, scale; transpose -------
__global__ __launch_bounds__(256) void pkt_kernel(const bf16* __restrict__ prov,
    const float* __restrict__ kbm, const float* __restrict__ gmax, bf16* __restrict__ pkT) {
  __shared__ bf16 lds[64][65];
  const int m0 = blockIdx.x * 64, nt = blockIdx.y, bh = blockIdx.z;
  const int n0 = nt * 64;
  const int t = threadIdx.x;
  float factor = expf(kbm[bh * 8 + nt] - gmax[0]);
  const bf16* src = prov + ((size_t)bh * 512 + n0) * 256 + m0;
#pragma unroll
  for (int c = 0; c < 16; c++) {
    int idx = c * 256 + t; int r = idx >> 6, cc = idx & 63;
    float pv = (float)src[(size_t)r * 256 + cc];
    lds[cc][r] = (bf16)((pv * factor + 1e-4f) * FEAT_SCALE);
  }
  __syncthreads();
  bf16* dst = pkT + ((size_t)bh * 256 + m0) * 512 + n0;
#pragma unroll
  for (int c = 0; c < 16; c++) {
    int idx = c * 256 + t; int r = idx >> 6, cc = idx & 63;
    dst[(size_t)r * 512 + cc] = lds[r][cc];
  }
}

// ---------------- vT[bh,e,n] = qkv[b,n,1536+h*96+e] ----------------
__global__ __launch_bounds__(256) void vt_kernel(const bf16* __restrict__ qkv, bf16* __restrict__ vT) {
  __shared__ bf16 lds[64][97];
  int bh = blockIdx.y, b = bh >> 3, h = bh & 7;
  int n0 = blockIdx.x * 64;
  int t = threadIdx.x;
  const bf16* src = qkv + ((size_t)b * 512 + n0) * 2304 + 1536 + h * 96;
  for (int idx = t; idx < 6144; idx += 256) {
    int r = idx / 96, c = idx % 96;
    lds[r][c] = src[(size_t)r * 2304 + c];
  }
  __syncthreads();
  bf16* dst = vT + (size_t)bh * 96 * 512 + n0;
  for (int idx = t; idx < 6144; idx += 256) {
    int e = idx >> 6, nn = idx & 63;
    dst[(size_t)e * 512 + nn] = lds[nn][e];
  }
}

// ---------------- ctx GEMM + fused ksum: ctxT[bh,e,m], ksum[bh,m]=sum_n pkT[m,n] -------
__global__ __launch_bounds__(256) void ctx_gemm(const bf16* __restrict__ pkT,
    const bf16* __restrict__ vT, bf16* __restrict__ ctxT, float* __restrict__ ksum) {
  __shared__ __attribute__((aligned(16))) bf16 lds_a[64 * 40];
  __shared__ __attribute__((aligned(16))) bf16 lds_b[96 * 40];
  const int t = threadIdx.x;
  const int bh = blockIdx.y, m0 = blockIdx.x * 64;
  const bf16* A = pkT + (size_t)bh * 256 * 512;
  const bf16* B = vT + (size_t)bh * 96 * 512;
  const int wave = t >> 6, lane = t & 63;
  const int quad = lane >> 4, id = lane & 15;
  const int row = t >> 2, kof = (t & 3) * 8;
  f32x4 acc[6] = {};
  float ks = 0.f;
  for (int k0 = 0; k0 < 512; k0 += 32) {
    *(bf16x8*)&lds_a[row * 40 + kof] = *(const bf16x8*)&A[(size_t)(m0 + row) * 512 + k0 + kof];
    for (int idx = t; idx < 384; idx += 256) {
      int r2 = idx >> 2, k2 = (idx & 3) * 8;
      *(bf16x8*)&lds_b[r2 * 40 + k2] = *(const bf16x8*)&B[(size_t)r2 * 512 + k0 + k2];
    }
    __syncthreads();
    bf16x8 af = *(bf16x8*)&lds_a[(wave * 16 + id) * 40 + quad * 8];
#pragma unroll
    for (int e = 0; e < 8; e++) ks += (float)af[e];
#pragma unroll
    for (int j = 0; j < 6; j++) {
      bf16x8 bg = *(bf16x8*)&lds_b[(j * 16 + id) * 40 + quad * 8];
      acc[j] = __builtin_amdgcn_mfma_f32_16x16x32_bf16(af, bg, acc[j], 0, 0, 0);
    }
    __syncthreads();
  }
  ks += __shfl_xor(ks, 16, 64);
  ks += __shfl_xor(ks, 32, 64);
  if (quad == 0) ksum[bh * 256 + m0 + wave * 16 + id] = ks;
#pragma unroll
  for (int j = 0; j < 6; j++)
#pragma unroll
    for (int r = 0; r < 4; r++) {
      int e = j * 16 + id;
      int m = m0 + wave * 16 + quad * 4 + r;
      ctxT[((size_t)bh * 96 + e) * 256 + m] = (bf16)acc[j][r];
    }
}

// ---------------- out GEMM + fused den: attn = (pq @ ctxT^T) / (pq . ksum) -------------
__global__ __launch_bounds__(256) void out_gemm(const bf16* __restrict__ pq,
    const bf16* __restrict__ ctxT, const float* __restrict__ ksum, bf16* __restrict__ attn) {
  __shared__ __attribute__((aligned(16))) bf16 lds_a[64 * 40];
  __shared__ __attribute__((aligned(16))) bf16 lds_b[96 * 40];
  __shared__ float den_lds[64];
  const int t = threadIdx.x;
  const int bh = blockIdx.y, m0 = blockIdx.x * 64;
  const int b = bh >> 3, h = bh & 7;
  const bf16* A = pq + (size_t)bh * 512 * 256;
  const bf16* B = ctxT + (size_t)bh * 96 * 256;
  const int wave = t >> 6, lane = t & 63;
  const int quad = lane >> 4, id = lane & 15;
  const int row = t >> 2, kof = (t & 3) * 8;
  f32x4 acc[6] = {};
  float den = 0.f;
  for (int k0 = 0; k0 < 256; k0 += 32) {
    *(bf16x8*)&lds_a[row * 40 + kof] = *(const bf16x8*)&A[(size_t)(m0 + row) * 256 + k0 + kof];
    for (int idx = t; idx < 384; idx += 256) {
      int r2 = idx >> 2, k2 = (idx & 3) * 8;
      *(bf16x8*)&lds_b[r2 * 40 + k2] = *(const bf16x8*)&B[(size_t)r2 * 256 + k0 + k2];
    }
    __syncthreads();
    bf16x8 af = *(bf16x8*)&lds_a[(wave * 16 + id) * 40 + quad * 8];
    const f32x4* kp = (const f32x4*)(ksum + bh * 256 + k0 + quad * 8);
    f32x4 k0v = kp[0], k1v = kp[1];
#pragma unroll
    for (int e = 0; e < 4; e++) den += (float)af[e] * k0v[e];
#pragma unroll
    for (int e = 0; e < 4; e++) den += (float)af[e + 4] * k1v[e];
#pragma unroll
    for (int j = 0; j < 6; j++) {
      bf16x8 bg = *(bf16x8*)&lds_b[(j * 16 + id) * 40 + quad * 8];
      acc[j] = __builtin_amdgcn_mfma_f32_16x16x32_bf16(af, bg, acc[j], 0, 0, 0);
    }
    __syncthreads();
  }
  den += __shfl_xor(den, 16, 64);
  den += __shfl_xor(den, 32, 64);
  if (quad == 0) den_lds[wave * 16 + id] = den;
  __syncthreads();
#pragma unroll
  for (int j = 0; j < 6; j++)
#pragma unroll
    for (int r = 0; r < 4; r++) {
      int e = j * 16 + id;
      int n = m0 + wave * 16 + quad * 4 + r;
      float v = acc[j][r] / fmaxf(den_lds[wave * 16 + quad * 4 + r], 1e-30f);
      attn[((size_t)(b * 512 + n)) * 768 + h * 96 + e] = (bf16)v;
    }
}

// ---------------- final head ----------------
__global__ __launch_bounds__(256) void mask_kernel(const float* __restrict__ x,
    const float* __restrict__ mw, const float* __restrict__ mb, float* __restrict__ out) {
  int row = blockIdx.x * 4 + (threadIdx.x >> 6);
  int lane = threadIdx.x & 63;
  int b = row >> 9, n = row & 511;
  const float* xr = x + (size_t)row * 768;
  float a0 = 0, a1 = 0, a2 = 0, a3 = 0;
  for (int d = lane; d < 768; d += 64) {
    float xv = xr[d];
    a0 += xv * mw[d * 4 + 0];
    a1 += xv * mw[d * 4 + 1];
    a2 += xv * mw[d * 4 + 2];
    a3 += xv * mw[d * 4 + 3];
  }
  a0 = waveSum(a0); a1 = waveSum(a1); a2 = waveSum(a2); a3 = waveSum(a3);
  if (lane == 0) {
    out[((size_t)b * 4 + 0) * 512 + n] = 1.f / (1.f + expf(-(a0 + mb[0])));
    out[((size_t)b * 4 + 1) * 512 + n] = 1.f / (1.f + expf(-(a1 + mb[1])));
    out[((size_t)b * 4 + 2) * 512 + n] = 1.f / (1.f + expf(-(a2 + mb[2])));
    out[((size_t)b * 4 + 3) * 512 + n] = 1.f / (1.f + expf(-(a3 + mb[3])));
  }
}

extern "C" void kernel_launch(void* const* d_in, const int* in_sizes, int n_in,
                              void* d_out, int out_size, void* d_ws, size_t ws_size,
                              hipStream_t stream) {
  const float* mel     = (const float*)d_in[0];
  const float* patch_w = (const float*)d_in[1];
  const float* patch_b = (const float*)d_in[2];
  const float* pos     = (const float*)d_in[3];
  const float* proj    = (const float*)d_in[4];
  const float* ln1_s   = (const float*)d_in[5];
  const float* ln1_b   = (const float*)d_in[6];
  const float* qkv_w   = (const float*)d_in[7];
  const float* qkv_b   = (const float*)d_in[8];
  const float* ao_w    = (const float*)d_in[9];
  const float* ao_b    = (const float*)d_in[10];
  const float* ln2_s   = (const float*)d_in[11];
  const float* ln2_b   = (const float*)d_in[12];
  const float* ff1_w   = (const float*)d_in[13];
  const float* ff1_b   = (const float*)d_in[14];
  const float* ff2_w   = (const float*)d_in[15];
  const float* ff2_b   = (const float*)d_in[16];
  const float* mask_w  = (const float*)d_in[17];
  const float* mask_b  = (const float*)d_in[18];

  char* ws = (char*)d_ws;
  size_t off = 0;
  auto alloc = [&](size_t bytes) { void* p = ws + off; off += (bytes + 255) & ~(size_t)255; return p; };
  float* x     = (float*)alloc(4096ull * 768 * 4);
  bf16* h      = (bf16*)alloc(4096ull * 768 * 2);
  bf16* qkv    = (bf16*)alloc(4096ull * 2304 * 2);
  bf16* wtq    = (bf16*)alloc(2304ull * 768 * 2);
  bf16* wta    = (bf16*)alloc(768ull * 768 * 2);
  bf16* wtf1   = (bf16*)alloc(3072ull * 768 * 2);
  bf16* wtf2   = (bf16*)alloc(768ull * 3072 * 2);
  bf16* patches= (bf16*)alloc(4096ull * 256 * 2);
  bf16* pwb    = (bf16*)alloc(768ull * 256 * 2);
  bf16* projb  = (bf16*)alloc(256ull * 96 * 2);
  bf16* pq     = (bf16*)alloc(8388608ull * 2);
  bf16* prov   = (bf16*)alloc(8388608ull * 2);
  bf16* pkT    = (bf16*)alloc(8388608ull * 2);
  bf16* vT     = (bf16*)alloc(64ull * 96 * 512 * 2);
  bf16* ctxT   = (bf16*)alloc(64ull * 96 * 256 * 2);
  float* ksum  = (float*)alloc(64ull * 256 * 4);
  float* kbm   = (float*)alloc(512ull * 4);
  float* gmax  = (float*)alloc(256);
  bf16* attn   = (bf16*)alloc(4096ull * 768 * 2);
  bf16* ffh    = (bf16*)alloc(4096ull * 3072 * 2);
  if (ws_size < off) return;  // clean fail instead of corruption

  patches_kernel<<<4096, 256, 0, stream>>>(mel, patches);
  cvt_kernel<<<768, 256, 0, stream>>>(patch_w, pwb, 196608);
  cvt_kernel<<<96, 256, 0, stream>>>(proj, projb, 24576);
  gemm128<<<dim3(32, 6), 256, 0, stream>>>(patches, pwb, patch_b, nullptr, x, pos,
                                           768, 256, 3);

  for (int l = 0; l < 6; l++) {
    transpose_cvt_kernel<<<dim3(36, 12), 256, 0, stream>>>(qkv_w + (size_t)l * 768 * 2304, wtq, 768, 2304);
    transpose_cvt_kernel<<<dim3(12, 12), 256, 0, stream>>>(ao_w + (size_t)l * 768 * 768, wta, 768, 768);
    transpose_cvt_kernel<<<dim3(48, 12), 256, 0, stream>>>(ff1_w + (size_t)l * 768 * 3072, wtf1, 768, 3072);
    transpose_cvt_kernel<<<dim3(12, 48), 256, 0, stream>>>(ff2_w + (size_t)l * 3072 * 768, wtf2, 3072, 768);

    ln_kernel<<<4096, 256, 0, stream>>>(x, ln1_s + l * 768, ln1_b + l * 768, h);
    gemm128<<<dim3(32, 18), 256, 0, stream>>>(h, wtq, qkv_b + l * 2304, qkv, nullptr,
                                              nullptr, 2304, 768, 0);

    phi_q_kernel<<<dim3(8, 64), 256, 0, stream>>>(qkv, projb, pq);
    phi_k_kernel<<<dim3(8, 64), 256, 0, stream>>>(qkv, projb, prov, kbm);
    kred_kernel<<<1, 256, 0, stream>>>(kbm, gmax);
    pkt_kernel<<<dim3(4, 8, 64), 256, 0, stream>>>(prov, kbm, gmax, pkT);
    vt_kernel<<<dim3(8, 64), 256, 0, stream>>>(qkv, vT);
    ctx_gemm<<<dim3(4, 64), 256, 0, stream>>>(pkT, vT, ctxT, ksum);
    out_gemm<<<dim3(8, 64), 256, 0, stream>>>(pq, ctxT, ksum, attn);
    // x += attn @ ao_w + ao_b   (split-K=4, atomic accumulate into residual)
    gemm128<<<dim3(32, 6, 4), 256, 0, stream>>>(attn, wta, ao_b + l * 768, nullptr, x,
                                                nullptr, 768, 192, 4);

    ln_kernel<<<4096, 256, 0, stream>>>(x, ln2_s + l * 768, ln2_b + l * 768, h);
    gemm128<<<dim3(32, 24), 256, 0, stream>>>(h, wtf1, ff1_b + l * 3072, ffh, nullptr,
                                              nullptr, 3072, 768, 1);
    // x += ffh @ ff2_w + ff2_b   (split-K=4, atomic accumulate into residual)
    gemm128<<<dim3(32, 6, 4), 256, 0, stream>>>(ffh, wtf2, ff2_b + l * 768, nullptr, x,
                                                nullptr, 768, 768, 4);
  }

  mask_kernel<<<1024, 256, 0, stream>>>(x, mask_w, mask_b, (float*)d_out);
}

// Round 5
// 1743.080 us; speedup vs baseline: 1.5723x; 1.1440x over previous
//
#include <hip/hip_runtime.h>
#include <hip/hip_bf16.h>

typedef __bf16 bf16;
typedef __bf16 bf16x8 __attribute__((ext_vector_type(8)));
typedef float f32x4 __attribute__((ext_vector_type(4)));
typedef unsigned int u32;

#define PHI_SCALE  0.31947154f   // 96^-0.25
#define DIAG_SCALE 0.05103104f   // 0.5 * 96^-0.5
#define FEAT_SCALE 0.0625f       // 256^-0.5

// async global->LDS, 16B per lane; LDS dest = wave-uniform base + lane*16
__device__ __forceinline__ void glds16(const bf16* g, bf16* l) {
  __builtin_amdgcn_global_load_lds(
      (const __attribute__((address_space(1))) u32*)g,
      (__attribute__((address_space(3))) u32*)l, 16, 0, 0);
}

// ---------------- reductions ----------------
__device__ __forceinline__ float waveSum(float v) {
#pragma unroll
  for (int o = 32; o > 0; o >>= 1) v += __shfl_xor(v, o, 64);
  return v;
}
__device__ __forceinline__ float waveMax(float v) {
#pragma unroll
  for (int o = 32; o > 0; o >>= 1) v = fmaxf(v, __shfl_xor(v, o, 64));
  return v;
}
__device__ __forceinline__ float blockSum(float v) {
  __shared__ float tmp[4];
  v = waveSum(v);
  if ((threadIdx.x & 63) == 0) tmp[threadIdx.x >> 6] = v;
  __syncthreads();
  float r = tmp[0] + tmp[1] + tmp[2] + tmp[3];
  __syncthreads();
  return r;
}
__device__ __forceinline__ float blockMax(float v) {
  __shared__ float tmp[4];
  v = waveMax(v);
  if ((threadIdx.x & 63) == 0) tmp[threadIdx.x >> 6] = v;
  __syncthreads();
  float r = fmaxf(fmaxf(tmp[0], tmp[1]), fmaxf(tmp[2], tmp[3]));
  __syncthreads();
  return r;
}

// ---------------- patch gather: mel f32 -> patches bf16 (4096 x 256) ----------------
__global__ __launch_bounds__(256) void patches_kernel(const float* __restrict__ mel,
    bf16* __restrict__ patches) {
  int blk = blockIdx.x, t = threadIdx.x;
  int b = blk >> 9, n = blk & 511;
  int r0 = (n >> 3) << 4, c0 = (n & 7) << 4;
  patches[(size_t)blk * 256 + t] =
      (bf16)mel[((size_t)b * 1024 + r0 + (t >> 4)) * 128 + c0 + (t & 15)];
}

// ---------------- f32 -> bf16 convert ----------------
__global__ __launch_bounds__(256) void cvt_kernel(const float* __restrict__ src,
    bf16* __restrict__ dst, int n) {
  int i = blockIdx.x * 256 + threadIdx.x;
  if (i < n) dst[i] = (bf16)src[i];
}

// ---------------- transpose + convert: src f32 (K x N) -> dst bf16 (N x K) ----------------
__global__ __launch_bounds__(256) void transpose_cvt_kernel(const float* __restrict__ src,
    bf16* __restrict__ dst, int K, int N) {
  __shared__ float lds[64][65];
  int n0 = blockIdx.x * 64, k0 = blockIdx.y * 64;
  int t = threadIdx.x;
  for (int idx = t; idx < 4096; idx += 256) {
    int r = idx >> 6, c = idx & 63;
    lds[r][c] = src[(size_t)(k0 + r) * N + n0 + c];
  }
  __syncthreads();
  for (int idx = t; idx < 4096; idx += 256) {
    int r = idx >> 6, c = idx & 63;
    dst[(size_t)(n0 + r) * K + k0 + c] = (bf16)lds[c][r];
  }
}

// ---------------- layernorm: x(f32, rows x 768) -> h(bf16) ----------------
__global__ __launch_bounds__(256) void ln_kernel(const float* __restrict__ x,
    const float* __restrict__ s, const float* __restrict__ bta, bf16* __restrict__ h) {
  int row = blockIdx.x;
  const float* xr = x + (size_t)row * 768;
  int t = threadIdx.x;
  float v0 = xr[t], v1 = xr[t + 256], v2 = xr[t + 512];
  float mu = blockSum(v0 + v1 + v2) * (1.f / 768.f);
  float d0 = v0 - mu, d1 = v1 - mu, d2 = v2 - mu;
  float var = blockSum(d0 * d0 + d1 * d1 + d2 * d2) * (1.f / 768.f);
  float inv = rsqrtf(var + 1e-5f);
  bf16* hr = h + (size_t)row * 768;
  hr[t]       = (bf16)(d0 * inv * s[t]       + bta[t]);
  hr[t + 256] = (bf16)(d1 * inv * s[t + 256] + bta[t + 256]);
  hr[t + 512] = (bf16)(d2 * inv * s[t + 512] + bta[t + 512]);
}

// ---------------- main MFMA GEMM: BM=128, BN=64, BK=32, glds staging ----------------
// C(MxN) = A(MxK,row bf16) @ B(NxK,row bf16)^T ; K split over gridDim.z (kchunk each)
// Wave w owns m-rows [32w,32w+32) x all 64 n. Grid-limited occupancy fix: 2x blocks
// vs 128x128 tile at same MFMA/CU (latency-bound regime, MfmaUtil was 10%).
// mode 0: outb=bf16(v); 1: outb=bf16(gelu(v)); 3: xout=v+pos; 4: atomicAdd(xout, v)
__global__ __launch_bounds__(256) void gemm_b64(const bf16* __restrict__ A,
    const bf16* __restrict__ B, const float* __restrict__ bias,
    bf16* __restrict__ outb, float* __restrict__ xout,
    const float* __restrict__ pos, int N, int kchunk, int mode) {
  __shared__ __attribute__((aligned(16))) bf16 lds_a[128 * 32];
  __shared__ __attribute__((aligned(16))) bf16 lds_b[64 * 32];
  const int t = threadIdx.x;
  const int m0 = blockIdx.x * 128, n0 = blockIdx.y * 64;
  const int kz = blockIdx.z;
  const int k_start = kz * kchunk;
  const int wave = t >> 6, lane = t & 63;
  const int quad = lane >> 4, id = lane & 15;
  const int srow = lane >> 2, scol = (lane & 3) * 8;
  const int K = kchunk * gridDim.z;
  const bf16* pa0 = A + (size_t)(m0 + wave * 32 + srow) * K + k_start + scol;
  const bf16* pa1 = pa0 + (size_t)16 * K;
  const bf16* pb  = B + (size_t)(n0 + wave * 16 + srow) * K + k_start + scol;
  bf16* la0 = lds_a + wave * 1024;
  bf16* la1 = la0 + 512;
  bf16* lb  = lds_b + wave * 512;
  f32x4 acc[2][4] = {};
  for (int k0 = 0; k0 < kchunk; k0 += 32) {
    glds16(pa0, la0); glds16(pa1, la1); glds16(pb, lb);
    pa0 += 32; pa1 += 32; pb += 32;
    __syncthreads();
    bf16x8 af[2], bg[4];
#pragma unroll
    for (int i = 0; i < 2; i++) af[i] = *(bf16x8*)&lds_a[(wave * 32 + i * 16 + id) * 32 + quad * 8];
#pragma unroll
    for (int j = 0; j < 4; j++) bg[j] = *(bf16x8*)&lds_b[(j * 16 + id) * 32 + quad * 8];
#pragma unroll
    for (int i = 0; i < 2; i++)
#pragma unroll
      for (int j = 0; j < 4; j++)
        acc[i][j] = __builtin_amdgcn_mfma_f32_16x16x32_bf16(af[i], bg[j], acc[i][j], 0, 0, 0);
    __syncthreads();
  }
#pragma unroll
  for (int i = 0; i < 2; i++) {
#pragma unroll
    for (int j = 0; j < 4; j++) {
#pragma unroll
      for (int r = 0; r < 4; r++) {
        int rr = m0 + wave * 32 + i * 16 + quad * 4 + r;
        int cc = n0 + j * 16 + id;
        if (mode == 4) {
          float v = acc[i][j][r] + (kz == 0 ? bias[cc] : 0.f);
          atomicAdd(&xout[(size_t)rr * N + cc], v);
        } else {
          float v = acc[i][j][r] + bias[cc];
          if (mode == 0) {
            outb[(size_t)rr * N + cc] = (bf16)v;
          } else if (mode == 1) {
            outb[(size_t)rr * N + cc] = (bf16)(0.5f * v * (1.0f + erff(v * 0.70710678f)));
          } else {
            xout[(size_t)rr * N + cc] = v + pos[(size_t)(rr & 511) * 768 + cc];
          }
        }
      }
    }
  }
}

// ---------------- fused phi_q: u=qs@proj^T, diag from sumsq, row-max, exp -> pq bf16 ----
__global__ __launch_bounds__(256) void phi_q_kernel(const bf16* __restrict__ qkv,
    const bf16* __restrict__ proj, bf16* __restrict__ pq) {
  __shared__ __attribute__((aligned(16))) bf16 lA[3][64 * 32];
  __shared__ __attribute__((aligned(16))) bf16 lB[3][256 * 32];
  __shared__ float sqlds[64];
  const int t = threadIdx.x;
  const int nt = blockIdx.x, bh = blockIdx.y;
  const int b = bh >> 3, h = bh & 7;
  const int n0 = nt * 64;
  const bf16* Abase = qkv + ((size_t)(b * 512 + n0)) * 2304 + h * 96;
#pragma unroll
  for (int c = 0; c < 3; c++) {
    int v = c * 256 + t;
    int row = v / 12, s = v % 12;
    *(bf16x8*)&lA[s >> 2][row * 32 + (s & 3) * 8] = *(const bf16x8*)&Abase[(size_t)row * 2304 + s * 8];
  }
#pragma unroll
  for (int c = 0; c < 12; c++) {
    int v = c * 256 + t;
    int row = v / 12, s = v % 12;
    *(bf16x8*)&lB[s >> 2][row * 32 + (s & 3) * 8] = *(const bf16x8*)&proj[(size_t)row * 96 + s * 8];
  }
  __syncthreads();
  const int wave = t >> 6, lane = t & 63, quad = lane >> 4, id = lane & 15;
  f32x4 acc[16] = {};
  float sq = 0.f;
#pragma unroll
  for (int kb = 0; kb < 3; kb++) {
    bf16x8 af = *(bf16x8*)&lA[kb][(wave * 16 + id) * 32 + quad * 8];
#pragma unroll
    for (int e = 0; e < 8; e++) { float fv = (float)af[e]; sq += fv * fv; }
#pragma unroll
    for (int j = 0; j < 16; j++) {
      bf16x8 bg = *(bf16x8*)&lB[kb][(j * 16 + id) * 32 + quad * 8];
      acc[j] = __builtin_amdgcn_mfma_f32_16x16x32_bf16(af, bg, acc[j], 0, 0, 0);
    }
  }
  sq += __shfl_xor(sq, 16, 64);
  sq += __shfl_xor(sq, 32, 64);
  if (quad == 0) sqlds[wave * 16 + id] = sq;
  __syncthreads();
#pragma unroll
  for (int r = 0; r < 4; r++) {
    int rrow = quad * 4 + r;
    float dg = DIAG_SCALE * sqlds[wave * 16 + rrow];
    float mx = -1e30f;
#pragma unroll
    for (int j = 0; j < 16; j++) mx = fmaxf(mx, acc[j][r]);
    mx = fmaxf(mx, __shfl_xor(mx, 1, 64));
    mx = fmaxf(mx, __shfl_xor(mx, 2, 64));
    mx = fmaxf(mx, __shfl_xor(mx, 4, 64));
    mx = fmaxf(mx, __shfl_xor(mx, 8, 64));
    float umax = mx * PHI_SCALE;
#pragma unroll
    for (int j = 0; j < 16; j++) {
      float uu = acc[j][r] * PHI_SCALE;
      float val = (expf(uu - dg - umax) + 1e-4f) * FEAT_SCALE;
      pq[((size_t)bh * 512 + n0 + wave * 16 + rrow) * 256 + j * 16 + id] = (bf16)val;
    }
  }
}

// ---------------- fused phi_k: u, diag, block-max; prov=exp(u-diag-blkmax) bf16 --------
__global__ __launch_bounds__(256) void phi_k_kernel(const bf16* __restrict__ qkv,
    const bf16* __restrict__ proj, bf16* __restrict__ prov, float* __restrict__ kbm) {
  __shared__ __attribute__((aligned(16))) bf16 lA[3][64 * 32];
  __shared__ __attribute__((aligned(16))) bf16 lB[3][256 * 32];
  __shared__ float sqlds[64];
  __shared__ float bmax4[4];
  const int t = threadIdx.x;
  const int nt = blockIdx.x, bh = blockIdx.y;
  const int b = bh >> 3, h = bh & 7;
  const int n0 = nt * 64;
  const bf16* Abase = qkv + ((size_t)(b * 512 + n0)) * 2304 + 768 + h * 96;
#pragma unroll
  for (int c = 0; c < 3; c++) {
    int v = c * 256 + t;
    int row = v / 12, s = v % 12;
    *(bf16x8*)&lA[s >> 2][row * 32 + (s & 3) * 8] = *(const bf16x8*)&Abase[(size_t)row * 2304 + s * 8];
  }
#pragma unroll
  for (int c = 0; c < 12; c++) {
    int v = c * 256 + t;
    int row = v / 12, s = v % 12;
    *(bf16x8*)&lB[s >> 2][row * 32 + (s & 3) * 8] = *(const bf16x8*)&proj[(size_t)row * 96 + s * 8];
  }
  __syncthreads();
  const int wave = t >> 6, lane = t & 63, quad = lane >> 4, id = lane & 15;
  f32x4 acc[16] = {};
  float sq = 0.f;
#pragma unroll
  for (int kb = 0; kb < 3; kb++) {
    bf16x8 af = *(bf16x8*)&lA[kb][(wave * 16 + id) * 32 + quad * 8];
#pragma unroll
    for (int e = 0; e < 8; e++) { float fv = (float)af[e]; sq += fv * fv; }
#pragma unroll
    for (int j = 0; j < 16; j++) {
      bf16x8 bg = *(bf16x8*)&lB[kb][(j * 16 + id) * 32 + quad * 8];
      acc[j] = __builtin_amdgcn_mfma_f32_16x16x32_bf16(af, bg, acc[j], 0, 0, 0);
    }
  }
  sq += __shfl_xor(sq, 16, 64);
  sq += __shfl_xor(sq, 32, 64);
  if (quad == 0) sqlds[wave * 16 + id] = sq;
  float bm = -1e30f;
#pragma unroll
  for (int j = 0; j < 16; j++)
#pragma unroll
    for (int r = 0; r < 4; r++) bm = fmaxf(bm, acc[j][r]);
  bm = waveMax(bm);
  if (lane == 0) bmax4[wave] = bm;
  __syncthreads();
  float blkmax = fmaxf(fmaxf(bmax4[0], bmax4[1]), fmaxf(bmax4[2], bmax4[3])) * PHI_SCALE;
  if (t == 0) kbm[bh * 8 + nt] = blkmax;
#pragma unroll
  for (int r = 0; r < 4; r++) {
    int rrow = quad * 4 + r;
    float dg = DIAG_SCALE * sqlds[wave * 16 + rrow];
#pragma unroll
    for (int j = 0; j < 16; j++) {
      float uu = acc[j][r] * PHI_SCALE;
      prov[((size_t)bh * 512 + n0 + wave * 16 + rrow) * 256 + j * 16 + id] =
          (bf16)expf(uu - dg - blkmax);
    }
  }
}

// ---------------- global max over kbm[512] ----------------
__global__ __launch_bounds__(256) void kred_kernel(const float* __restrict__ kbm,
    float* __restrict__ gmax) {
  int t = threadIdx.x;
  float m = fmaxf(kbm[t], kbm[t + 256]);
  m = blockMax(m);
  if (t == 0) gmax[0] = m;
}

// ---------------- pkT: rescale prov by exp(blkmax-gmax), +1e-4, scale; transpose -------
__global__ __launch_bounds__(256) void pkt_kernel(const bf16* __restrict__ prov,
    const float* __restrict__ kbm, const float* __restrict__ gmax, bf16* __restrict__ pkT) {
  __shared__ bf16 lds[64][65];
  const int m0 = blockIdx.x * 64, nt = blockIdx.y, bh = blockIdx.z;
  const int n0 = nt * 64;
  const int t = threadIdx.x;
  float factor = expf(kbm[bh * 8 + nt] - gmax[0]);
  const bf16* src = prov + ((size_t)bh * 512 + n0) * 256 + m0;
#pragma unroll
  for (int c = 0; c < 16; c++) {
    int idx = c * 256 + t; int r = idx >> 6, cc = idx & 63;
    float pv = (float)src[(size_t)r * 256 + cc];
    lds[cc][r] = (bf16)((pv * factor + 1e-4f) * FEAT_SCALE);
  }
  __syncthreads();
  bf16* dst = pkT + ((size_t)bh * 256 + m0) * 512 + n0;
#pragma unroll
  for (int c = 0; c < 16; c++) {
    int idx = c * 256 + t; int r = idx >> 6, cc = idx & 63;
    dst[(size_t)r * 512 + cc] = lds[r][cc];
  }
}

// ---------------- vT[bh,e,n] = qkv[b,n,1536+h*96+e] ----------------
__global__ __launch_bounds__(256) void vt_kernel(const bf16* __restrict__ qkv, bf16* __restrict__ vT) {
  __shared__ bf16 lds[64][97];
  int bh = blockIdx.y, b = bh >> 3, h = bh & 7;
  int n0 = blockIdx.x * 64;
  int t = threadIdx.x;
  const bf16* src = qkv + ((size_t)b * 512 + n0) * 2304 + 1536 + h * 96;
  for (int idx = t; idx < 6144; idx += 256) {
    int r = idx / 96, c = idx % 96;
    lds[r][c] = src[(size_t)r * 2304 + c];
  }
  __syncthreads();
  bf16* dst = vT + (size_t)bh * 96 * 512 + n0;
  for (int idx = t; idx < 6144; idx += 256) {
    int e = idx >> 6, nn = idx & 63;
    dst[(size_t)e * 512 + nn] = lds[nn][e];
  }
}

// ---------------- ctx GEMM + fused ksum: ctxT[bh,e,m], ksum[bh,m]=sum_n pkT[m,n] -------
__global__ __launch_bounds__(256) void ctx_gemm(const bf16* __restrict__ pkT,
    const bf16* __restrict__ vT, bf16* __restrict__ ctxT, float* __restrict__ ksum) {
  __shared__ __attribute__((aligned(16))) bf16 lds_a[64 * 40];
  __shared__ __attribute__((aligned(16))) bf16 lds_b[96 * 40];
  const int t = threadIdx.x;
  const int bh = blockIdx.y, m0 = blockIdx.x * 64;
  const bf16* A = pkT + (size_t)bh * 256 * 512;
  const bf16* B = vT + (size_t)bh * 96 * 512;
  const int wave = t >> 6, lane = t & 63;
  const int quad = lane >> 4, id = lane & 15;
  const int row = t >> 2, kof = (t & 3) * 8;
  f32x4 acc[6] = {};
  float ks = 0.f;
  for (int k0 = 0; k0 < 512; k0 += 32) {
    *(bf16x8*)&lds_a[row * 40 + kof] = *(const bf16x8*)&A[(size_t)(m0 + row) * 512 + k0 + kof];
    for (int idx = t; idx < 384; idx += 256) {
      int r2 = idx >> 2, k2 = (idx & 3) * 8;
      *(bf16x8*)&lds_b[r2 * 40 + k2] = *(const bf16x8*)&B[(size_t)r2 * 512 + k0 + k2];
    }
    __syncthreads();
    bf16x8 af = *(bf16x8*)&lds_a[(wave * 16 + id) * 40 + quad * 8];
#pragma unroll
    for (int e = 0; e < 8; e++) ks += (float)af[e];
#pragma unroll
    for (int j = 0; j < 6; j++) {
      bf16x8 bg = *(bf16x8*)&lds_b[(j * 16 + id) * 40 + quad * 8];
      acc[j] = __builtin_amdgcn_mfma_f32_16x16x32_bf16(af, bg, acc[j], 0, 0, 0);
    }
    __syncthreads();
  }
  ks += __shfl_xor(ks, 16, 64);
  ks += __shfl_xor(ks, 32, 64);
  if (quad == 0) ksum[bh * 256 + m0 + wave * 16 + id] = ks;
#pragma unroll
  for (int j = 0; j < 6; j++)
#pragma unroll
    for (int r = 0; r < 4; r++) {
      int e = j * 16 + id;
      int m = m0 + wave * 16 + quad * 4 + r;
      ctxT[((size_t)bh * 96 + e) * 256 + m] = (bf16)acc[j][r];
    }
}

// ---------------- out GEMM + fused den: attn = (pq @ ctxT^T) / (pq . ksum) -------------
__global__ __launch_bounds__(256) void out_gemm(const bf16* __restrict__ pq,
    const bf16* __restrict__ ctxT, const float* __restrict__ ksum, bf16* __restrict__ attn) {
  __shared__ __attribute__((aligned(16))) bf16 lds_a[64 * 40];
  __shared__ __attribute__((aligned(16))) bf16 lds_b[96 * 40];
  __shared__ float den_lds[64];
  const int t = threadIdx.x;
  const int bh = blockIdx.y, m0 = blockIdx.x * 64;
  const int b = bh >> 3, h = bh & 7;
  const bf16* A = pq + (size_t)bh * 512 * 256;
  const bf16* B = ctxT + (size_t)bh * 96 * 256;
  const int wave = t >> 6, lane = t & 63;
  const int quad = lane >> 4, id = lane & 15;
  const int row = t >> 2, kof = (t & 3) * 8;
  f32x4 acc[6] = {};
  float den = 0.f;
  for (int k0 = 0; k0 < 256; k0 += 32) {
    *(bf16x8*)&lds_a[row * 40 + kof] = *(const bf16x8*)&A[(size_t)(m0 + row) * 256 + k0 + kof];
    for (int idx = t; idx < 384; idx += 256) {
      int r2 = idx >> 2, k2 = (idx & 3) * 8;
      *(bf16x8*)&lds_b[r2 * 40 + k2] = *(const bf16x8*)&B[(size_t)r2 * 256 + k0 + k2];
    }
    __syncthreads();
    bf16x8 af = *(bf16x8*)&lds_a[(wave * 16 + id) * 40 + quad * 8];
    const f32x4* kp = (const f32x4*)(ksum + bh * 256 + k0 + quad * 8);
    f32x4 k0v = kp[0], k1v = kp[1];
#pragma unroll
    for (int e = 0; e < 4; e++) den += (float)af[e] * k0v[e];
#pragma unroll
    for (int e = 0; e < 4; e++) den += (float)af[e + 4] * k1v[e];
#pragma unroll
    for (int j = 0; j < 6; j++) {
      bf16x8 bg = *(bf16x8*)&lds_b[(j * 16 + id) * 40 + quad * 8];
      acc[j] = __builtin_amdgcn_mfma_f32_16x16x32_bf16(af, bg, acc[j], 0, 0, 0);
    }
    __syncthreads();
  }
  den += __shfl_xor(den, 16, 64);
  den += __shfl_xor(den, 32, 64);
  if (quad == 0) den_lds[wave * 16 + id] = den;
  __syncthreads();
#pragma unroll
  for (int j = 0; j < 6; j++)
#pragma unroll
    for (int r = 0; r < 4; r++) {
      int e = j * 16 + id;
      int n = m0 + wave * 16 + quad * 4 + r;
      float v = acc[j][r] / fmaxf(den_lds[wave * 16 + quad * 4 + r], 1e-30f);
      attn[((size_t)(b * 512 + n)) * 768 + h * 96 + e] = (bf16)v;
    }
}

// ---------------- final head ----------------
__global__ __launch_bounds__(256) void mask_kernel(const float* __restrict__ x,
    const float* __restrict__ mw, const float* __restrict__ mb, float* __restrict__ out) {
  int row = blockIdx.x * 4 + (threadIdx.x >> 6);
  int lane = threadIdx.x & 63;
  int b = row >> 9, n = row & 511;
  const float* xr = x + (size_t)row * 768;
  float a0 = 0, a1 = 0, a2 = 0, a3 = 0;
  for (int d = lane; d < 768; d += 64) {
    float xv = xr[d];
    a0 += xv * mw[d * 4 + 0];
    a1 += xv * mw[d * 4 + 1];
    a2 += xv * mw[d * 4 + 2];
    a3 += xv * mw[d * 4 + 3];
  }
  a0 = waveSum(a0); a1 = waveSum(a1); a2 = waveSum(a2); a3 = waveSum(a3);
  if (lane == 0) {
    out[((size_t)b * 4 + 0) * 512 + n] = 1.f / (1.f + expf(-(a0 + mb[0])));
    out[((size_t)b * 4 + 1) * 512 + n] = 1.f / (1.f + expf(-(a1 + mb[1])));
    out[((size_t)b * 4 + 2) * 512 + n] = 1.f / (1.f + expf(-(a2 + mb[2])));
    out[((size_t)b * 4 + 3) * 512 + n] = 1.f / (1.f + expf(-(a3 + mb[3])));
  }
}

extern "C" void kernel_launch(void* const* d_in, const int* in_sizes, int n_in,
                              void* d_out, int out_size, void* d_ws, size_t ws_size,
                              hipStream_t stream) {
  const float* mel     = (const float*)d_in[0];
  const float* patch_w = (const float*)d_in[1];
  const float* patch_b = (const float*)d_in[2];
  const float* pos     = (const float*)d_in[3];
  const float* proj    = (const float*)d_in[4];
  const float* ln1_s   = (const float*)d_in[5];
  const float* ln1_b   = (const float*)d_in[6];
  const float* qkv_w   = (const float*)d_in[7];
  const float* qkv_b   = (const float*)d_in[8];
  const float* ao_w    = (const float*)d_in[9];
  const float* ao_b    = (const float*)d_in[10];
  const float* ln2_s   = (const float*)d_in[11];
  const float* ln2_b   = (const float*)d_in[12];
  const float* ff1_w   = (const float*)d_in[13];
  const float* ff1_b   = (const float*)d_in[14];
  const float* ff2_w   = (const float*)d_in[15];
  const float* ff2_b   = (const float*)d_in[16];
  const float* mask_w  = (const float*)d_in[17];
  const float* mask_b  = (const float*)d_in[18];

  char* ws = (char*)d_ws;
  size_t off = 0;
  auto alloc = [&](size_t bytes) { void* p = ws + off; off += (bytes + 255) & ~(size_t)255; return p; };
  float* x     = (float*)alloc(4096ull * 768 * 4);
  bf16* h      = (bf16*)alloc(4096ull * 768 * 2);
  bf16* qkv    = (bf16*)alloc(4096ull * 2304 * 2);
  bf16* wtq    = (bf16*)alloc(2304ull * 768 * 2);
  bf16* wta    = (bf16*)alloc(768ull * 768 * 2);
  bf16* wtf1   = (bf16*)alloc(3072ull * 768 * 2);
  bf16* wtf2   = (bf16*)alloc(768ull * 3072 * 2);
  bf16* patches= (bf16*)alloc(4096ull * 256 * 2);
  bf16* pwb    = (bf16*)alloc(768ull * 256 * 2);
  bf16* projb  = (bf16*)alloc(256ull * 96 * 2);
  bf16* pq     = (bf16*)alloc(8388608ull * 2);
  bf16* prov   = (bf16*)alloc(8388608ull * 2);
  bf16* pkT    = (bf16*)alloc(8388608ull * 2);
  bf16* vT     = (bf16*)alloc(64ull * 96 * 512 * 2);
  bf16* ctxT   = (bf16*)alloc(64ull * 96 * 256 * 2);
  float* ksum  = (float*)alloc(64ull * 256 * 4);
  float* kbm   = (float*)alloc(512ull * 4);
  float* gmax  = (float*)alloc(256);
  bf16* attn   = (bf16*)alloc(4096ull * 768 * 2);
  bf16* ffh    = (bf16*)alloc(4096ull * 3072 * 2);
  if (ws_size < off) return;  // clean fail instead of corruption

  patches_kernel<<<4096, 256, 0, stream>>>(mel, patches);
  cvt_kernel<<<768, 256, 0, stream>>>(patch_w, pwb, 196608);
  cvt_kernel<<<96, 256, 0, stream>>>(proj, projb, 24576);
  gemm_b64<<<dim3(32, 12), 256, 0, stream>>>(patches, pwb, patch_b, nullptr, x, pos,
                                             768, 256, 3);

  for (int l = 0; l < 6; l++) {
    transpose_cvt_kernel<<<dim3(36, 12), 256, 0, stream>>>(qkv_w + (size_t)l * 768 * 2304, wtq, 768, 2304);
    transpose_cvt_kernel<<<dim3(12, 12), 256, 0, stream>>>(ao_w + (size_t)l * 768 * 768, wta, 768, 768);
    transpose_cvt_kernel<<<dim3(48, 12), 256, 0, stream>>>(ff1_w + (size_t)l * 768 * 3072, wtf1, 768, 3072);
    transpose_cvt_kernel<<<dim3(12, 48), 256, 0, stream>>>(ff2_w + (size_t)l * 3072 * 768, wtf2, 3072, 768);

    ln_kernel<<<4096, 256, 0, stream>>>(x, ln1_s + l * 768, ln1_b + l * 768, h);
    // qkv: (32,36) = 1152 blocks, 4.5/CU
    gemm_b64<<<dim3(32, 36), 256, 0, stream>>>(h, wtq, qkv_b + l * 2304, qkv, nullptr,
                                               nullptr, 2304, 768, 0);

    phi_q_kernel<<<dim3(8, 64), 256, 0, stream>>>(qkv, projb, pq);
    phi_k_kernel<<<dim3(8, 64), 256, 0, stream>>>(qkv, projb, prov, kbm);
    kred_kernel<<<1, 256, 0, stream>>>(kbm, gmax);
    pkt_kernel<<<dim3(4, 8, 64), 256, 0, stream>>>(prov, kbm, gmax, pkT);
    vt_kernel<<<dim3(8, 64), 256, 0, stream>>>(qkv, vT);
    ctx_gemm<<<dim3(4, 64), 256, 0, stream>>>(pkT, vT, ctxT, ksum);
    out_gemm<<<dim3(8, 64), 256, 0, stream>>>(pq, ctxT, ksum, attn);
    // x += attn @ ao_w + ao_b   (split-K=2, atomic accumulate, 768 blocks)
    gemm_b64<<<dim3(32, 12, 2), 256, 0, stream>>>(attn, wta, ao_b + l * 768, nullptr, x,
                                                  nullptr, 768, 384, 4);

    ln_kernel<<<4096, 256, 0, stream>>>(x, ln2_s + l * 768, ln2_b + l * 768, h);
    // ff1: (32,48) = 1536 blocks, 6/CU
    gemm_b64<<<dim3(32, 48), 256, 0, stream>>>(h, wtf1, ff1_b + l * 3072, ffh, nullptr,
                                               nullptr, 3072, 768, 1);
    // x += ffh @ ff2_w + ff2_b   (split-K=2, atomic accumulate, 768 blocks)
    gemm_b64<<<dim3(32, 12, 2), 256, 0, stream>>>(ffh, wtf2, ff2_b + l * 768, nullptr, x,
                                                  nullptr, 768, 1536, 4);
  }

  mask_kernel<<<1024, 256, 0, stream>>>(x, mask_w, mask_b, (float*)d_out);
}